// Round 11
// baseline (553.675 us; speedup 1.0000x reference)
//
#include <hip/hip_runtime.h>
#include <hip/hip_bf16.h>

// Problem constants (fixed by the reference)
#define NN 150000      // nodes
#define EE 600000      // edges
#define F_IN 32        // input node features
#define HD 128         // hidden dim
#define GG 2048        // graphs
#define CAP 28         // max degree bucket capacity (Poisson(4): P(deg>=28) ~ 4e-18)
#define NP 150016      // NN rounded up to 128-node blocks: 1172*128

typedef __attribute__((ext_vector_type(8))) short bf16x8;
typedef __attribute__((ext_vector_type(4))) float f32x4;
typedef __attribute__((address_space(1))) const void g1void;
typedef __attribute__((address_space(3))) void l3void;

__device__ inline void split_bf16(float v, unsigned short& hi, unsigned short& lo) {
    __hip_bfloat16 h = __float2bfloat16(v);
    float hv = __bfloat162float(h);
    __hip_bfloat16 l = __float2bfloat16(v - hv);
    hi = *reinterpret_cast<unsigned short*>(&h);
    lo = *reinterpret_cast<unsigned short*>(&l);
}
__device__ inline unsigned short bf16_hi(float v) {
    __hip_bfloat16 h = __float2bfloat16(v);
    return *reinterpret_cast<unsigned short*>(&h);
}
__device__ inline float bf2f(unsigned short u) {
    union { unsigned int i; float f; } c;
    c.i = ((unsigned int)u) << 16;
    return c.f;
}

// ---------------------------------------------------------------------------
// Zero-init for workspace regions
// ---------------------------------------------------------------------------
__global__ void init_zero(int* __restrict__ cnt_node, float* __restrict__ pooled) {
    int i = blockIdx.x * blockDim.x + threadIdx.x;
    if (i < NN) cnt_node[i] = 0;
    if (i < GG * HD) pooled[i] = 0.f;
}

// ---------------------------------------------------------------------------
// CSR-bucket build. AoS bucket[dst*CAP+slot].
// ---------------------------------------------------------------------------
__global__ void build_graph(const int* __restrict__ ei,
                            int* __restrict__ cnt_node,
                            int* __restrict__ bucket) {
    int e = blockIdx.x * blockDim.x + threadIdx.x;
    if (e >= EE) return;
    int src = ei[e];         // edge_index[0]
    int dst = ei[EE + e];    // edge_index[1]
    int slot = atomicAdd(&cnt_node[dst], 1);
    if (slot < CAP) bucket[dst * CAP + slot] = src;
}

// ---------------------------------------------------------------------------
// Weight prep: fp32 W[K][H] -> split-bf16 packed in LANE-LINEAR fragment order
// ---------------------------------------------------------------------------
struct PrepDesc { const float* src; unsigned short* dhi; unsigned short* dlo; int K; };
struct PrepArgs { PrepDesc d[9]; };

__global__ void prep_weights(PrepArgs pa) {
    PrepDesc de = pa.d[blockIdx.y];
    int total = de.K * HD;
    int KS = de.K >> 5;
    for (int idx = blockIdx.x * blockDim.x + threadIdx.x; idx < total;
         idx += gridDim.x * blockDim.x) {
        int k = idx / HD, h = idx - (idx / HD) * HD;   // src is [K][H]
        unsigned short hi, lo;
        split_bf16(de.src[idx], hi, lo);
        int nt = h >> 4, m = h & 15;
        int ks = k >> 5, quad = (k >> 3) & 3, e = k & 7;
        int lane = quad * 16 + m;
        int pidx = ((nt * KS + ks) * 64 + lane) * 8 + e;
        de.dhi[pidx] = hi;
        de.dlo[pidx] = lo;
    }
}

// ---------------------------------------------------------------------------
// Stage one nt-slice of weights (hi+lo tables) into LDS, cooperatively
// across 4 waves via global_load_lds (wave-uniform LDS base, per-lane gsrc).
// ---------------------------------------------------------------------------
template <int KS>
__device__ inline void stage_slice(const unsigned short* __restrict__ wh,
                                   const unsigned short* __restrict__ wl,
                                   int nt, unsigned short* dst, int wave, int lane) {
    if (KS == 4) {
        const unsigned short* gh = wh + nt * 2048 + wave * 512 + lane * 8;
        const unsigned short* gl = wl + nt * 2048 + wave * 512 + lane * 8;
        __builtin_amdgcn_global_load_lds((g1void*)gh, (l3void*)(dst + wave * 512), 16, 0, 0);
        __builtin_amdgcn_global_load_lds((g1void*)gl, (l3void*)(dst + 2048 + wave * 512), 16, 0, 0);
    } else {
        if (wave < 2) {
            const unsigned short* g = (wave == 0 ? wh : wl) + nt * 512 + lane * 8;
            __builtin_amdgcn_global_load_lds((g1void*)g, (l3void*)(dst + wave * 512), 16, 0, 0);
        }
    }
}

// ---------------------------------------------------------------------------
// Fused GIN layer (R11): R10 base (LDS-staged weights, 123us/layer verified)
// + two gather-phase fixes:
//  (1) MERGED-s masked gather (bf16): both 16-node groups' row loads issued
//      in the same loop round (2 slots x 2 s x 4 ks = 16 loads in flight,
//      both groups concurrent) to max(cnt0,cnt1), masked accumulate with
//      self-node-clamped indices (no OOB). R10's #pragma-unroll s-loop
//      serialized s=0's entire gather before s=1 (dynamic trip counts
//      block cross-loop interleave) -> only half the potential lines in
//      flight. R2's dedicated agg kernel proved ~1.7 TB/s is achievable
//      for this pattern at ~2x our in-flight depth.
//  (2) stage-1's first weight-slice DMA hoisted ABOVE the gather (runs
//      under the whole gather phase).
// VGPR rises ~108->~145: harmless (LDS 80KB binds occupancy at 2 blk/CU;
// bounds(256,2) caps alloc at 256 -> no spill). Tripwire: WRITE_SIZE.
// ---------------------------------------------------------------------------
template <int K_IN, bool BF16IN, bool POOL>
__launch_bounds__(256, 2)
__global__ void gin_layer(const void* __restrict__ hin_,
                          const int* __restrict__ cnt_node,
                          const int* __restrict__ bucket,
                          const unsigned short* __restrict__ w1h, const unsigned short* __restrict__ w1l,
                          const float* __restrict__ b1,
                          const unsigned short* __restrict__ w2h, const unsigned short* __restrict__ w2l,
                          const float* __restrict__ b2,
                          const unsigned short* __restrict__ w3h, const unsigned short* __restrict__ w3l,
                          const float* __restrict__ b3,
                          unsigned short* __restrict__ out,   // bf16 activations (non-pool)
                          const int* __restrict__ batch,
                          float* __restrict__ pooled) {
    constexpr int KS1 = K_IN / 32;
    // Per-wave, per-s swizzled transpose buffers: 4 x 2 x 16 x 128 u32 = 64 KB
    __shared__ unsigned int shp[4][2][16][128];
    // Double-buffered weight staging: 2 x 4096 hw = 16 KB
    __shared__ unsigned short ldsW[2][4096];

    const int wave = threadIdx.x >> 6;
    const int lane = threadIdx.x & 63;
    const int m = lane & 15;      // node row within a 16-set / out-feature col
    const int quad = lane >> 4;   // 0..3
    const int nodeBase = blockIdx.x * 128 + wave * 32;

    const float* hf = (const float*)hin_;
    const unsigned short* hb = (const unsigned short*)hin_;

    // Weight DMA for stage-1 nt=0 issued BEFORE the gather: runs underneath it.
    stage_slice<KS1>(w1h, w1l, 0, ldsW[0], wave, lane);

    // ---- aggregation: self + neighbors, fp32 accumulate ----
    float ag2[2][KS1][8];
    if (BF16IN) {
        int node0 = nodeBase + m;       node0 = node0 < NN ? node0 : NN - 1;
        int node1 = nodeBase + 16 + m;  node1 = node1 < NN ? node1 : NN - 1;
        const unsigned short* rs0 = hb + (size_t)node0 * K_IN + quad * 8;
        const unsigned short* rs1 = hb + (size_t)node1 * K_IN + quad * 8;
#pragma unroll
        for (int ks = 0; ks < KS1; ks++) {
            bf16x8 v0 = *(const bf16x8*)(rs0 + ks * 32);
            bf16x8 v1 = *(const bf16x8*)(rs1 + ks * 32);
#pragma unroll
            for (int e = 0; e < 8; e++) {
                ag2[0][ks][e] = bf2f((unsigned short)v0[e]);
                ag2[1][ks][e] = bf2f((unsigned short)v1[e]);
            }
        }
        int cnt0 = cnt_node[node0]; cnt0 = cnt0 < CAP ? cnt0 : CAP;
        int cnt1 = cnt_node[node1]; cnt1 = cnt1 < CAP ? cnt1 : CAP;
        const int* b0 = bucket + (size_t)node0 * CAP;
        const int* b1p = bucket + (size_t)node1 * CAP;
        int cmax = cnt0 > cnt1 ? cnt0 : cnt1;
#pragma unroll 1
        for (int i = 0; i < cmax; i += 2) {
            bool v0a = i < cnt0, v0b = i + 1 < cnt0;
            bool v1a = i < cnt1, v1b = i + 1 < cnt1;
            int t0a = b0[i], t0b = b0[i + 1];
            int t1a = b1p[i], t1b = b1p[i + 1];
            int j0a = v0a ? t0a : node0;
            int j0b = v0b ? t0b : node0;
            int j1a = v1a ? t1a : node1;
            int j1b = v1b ? t1b : node1;
            const unsigned short* r0a = hb + (size_t)j0a * K_IN + quad * 8;
            const unsigned short* r0b = hb + (size_t)j0b * K_IN + quad * 8;
            const unsigned short* r1a = hb + (size_t)j1a * K_IN + quad * 8;
            const unsigned short* r1b = hb + (size_t)j1b * K_IN + quad * 8;
            bf16x8 w0a[KS1], w0b[KS1], w1a[KS1], w1b[KS1];
#pragma unroll
            for (int ks = 0; ks < KS1; ks++) {
                w0a[ks] = *(const bf16x8*)(r0a + ks * 32);
                w0b[ks] = *(const bf16x8*)(r0b + ks * 32);
                w1a[ks] = *(const bf16x8*)(r1a + ks * 32);
                w1b[ks] = *(const bf16x8*)(r1b + ks * 32);
            }
#pragma unroll
            for (int ks = 0; ks < KS1; ks++)
#pragma unroll
                for (int e = 0; e < 8; e++) {
                    float x0a = v0a ? bf2f((unsigned short)w0a[ks][e]) : 0.f;
                    float x0b = v0b ? bf2f((unsigned short)w0b[ks][e]) : 0.f;
                    float x1a = v1a ? bf2f((unsigned short)w1a[ks][e]) : 0.f;
                    float x1b = v1b ? bf2f((unsigned short)w1b[ks][e]) : 0.f;
                    ag2[0][ks][e] += x0a + x0b;
                    ag2[1][ks][e] += x1a + x1b;
                }
        }
    } else {
        // fp32 input (layer 0, K=32): keep the verified per-s UN=8 loop
#pragma unroll
        for (int s = 0; s < 2; s++) {
            int node = nodeBase + s * 16 + m;
            node = node < NN ? node : NN - 1;
            const float* rs = hf + (size_t)node * K_IN + quad * 8;
            float4 v0 = *(const float4*)rs;
            float4 v1 = *(const float4*)(rs + 4);
            ag2[s][0][0] = v0.x; ag2[s][0][1] = v0.y; ag2[s][0][2] = v0.z; ag2[s][0][3] = v0.w;
            ag2[s][0][4] = v1.x; ag2[s][0][5] = v1.y; ag2[s][0][6] = v1.z; ag2[s][0][7] = v1.w;
            int cnt = cnt_node[node];
            cnt = cnt < CAP ? cnt : CAP;
            const int* b = bucket + (size_t)node * CAP;
            int i = 0;
            for (; i + 8 <= cnt; i += 8) {
                float4 a[8], c[8];
#pragma unroll
                for (int j = 0; j < 8; j++) {
                    const float* r = hf + (size_t)b[i + j] * K_IN + quad * 8;
                    a[j] = *(const float4*)r;
                    c[j] = *(const float4*)(r + 4);
                }
#pragma unroll
                for (int e = 0; e < 4; e++) {
                    float s01 = (&a[0].x)[e] + (&a[1].x)[e] + (&a[4].x)[e] + (&a[5].x)[e];
                    float s23 = (&a[2].x)[e] + (&a[3].x)[e] + (&a[6].x)[e] + (&a[7].x)[e];
                    ag2[s][0][e] += s01 + s23;
                }
#pragma unroll
                for (int e = 0; e < 4; e++) {
                    float s01 = (&c[0].x)[e] + (&c[1].x)[e] + (&c[4].x)[e] + (&c[5].x)[e];
                    float s23 = (&c[2].x)[e] + (&c[3].x)[e] + (&c[6].x)[e] + (&c[7].x)[e];
                    ag2[s][0][e + 4] += s01 + s23;
                }
            }
            for (; i < cnt; i++) {
                const float* r = hf + (size_t)b[i] * K_IN + quad * 8;
                float4 v0i = *(const float4*)r;
                float4 v1i = *(const float4*)(r + 4);
                ag2[s][0][0] += v0i.x; ag2[s][0][1] += v0i.y; ag2[s][0][2] += v0i.z; ag2[s][0][3] += v0i.w;
                ag2[s][0][4] += v1i.x; ag2[s][0][5] += v1i.y; ag2[s][0][6] += v1i.z; ag2[s][0][7] += v1i.w;
            }
        }
    }

    bf16x8 ah[2][KS1], al[2][KS1];
#pragma unroll
    for (int s = 0; s < 2; s++)
#pragma unroll
        for (int ks = 0; ks < KS1; ks++) {
            bf16x8 vh, vl;
#pragma unroll
            for (int e = 0; e < 8; e++) {
                unsigned short hi, lo;
                split_bf16(ag2[s][ks][e], hi, lo);
                vh[e] = (short)hi;
                vl[e] = (short)lo;
            }
            ah[s][ks] = vh;
            al[s][ks] = vl;
        }

    bf16x8 a2h[2][4], a2l[2][4];
    const int fxm = (m & 7) << 2;          // read-side swizzle for row m

    // ================= stage 1: LDS-staged weights, dual accumulators =======
    __syncthreads();
#pragma unroll 1
    for (int nt = 0; nt < 8; nt++) {
        int cur = nt & 1;
        if (nt < 7) stage_slice<KS1>(w1h, w1l, nt + 1, ldsW[cur ^ 1], wave, lane);
        bf16x8 bh[KS1], bl[KS1];
#pragma unroll
        for (int ks = 0; ks < KS1; ks++) {
            bh[ks] = *(const bf16x8*)&ldsW[cur][(ks * 64 + lane) * 8];
            bl[ks] = *(const bf16x8*)&ldsW[cur][KS1 * 512 + (ks * 64 + lane) * 8];
        }
        f32x4 c0 = {0.f, 0.f, 0.f, 0.f};
        f32x4 c1 = {0.f, 0.f, 0.f, 0.f};
#pragma unroll
        for (int ks = 0; ks < KS1; ks++) {
            c0 = __builtin_amdgcn_mfma_f32_16x16x32_bf16(ah[0][ks], bh[ks], c0, 0, 0, 0);
            c1 = __builtin_amdgcn_mfma_f32_16x16x32_bf16(ah[1][ks], bh[ks], c1, 0, 0, 0);
            c0 = __builtin_amdgcn_mfma_f32_16x16x32_bf16(al[0][ks], bh[ks], c0, 0, 0, 0);
            c1 = __builtin_amdgcn_mfma_f32_16x16x32_bf16(al[1][ks], bh[ks], c1, 0, 0, 0);
            c0 = __builtin_amdgcn_mfma_f32_16x16x32_bf16(ah[0][ks], bl[ks], c0, 0, 0, 0);
            c1 = __builtin_amdgcn_mfma_f32_16x16x32_bf16(ah[1][ks], bl[ks], c1, 0, 0, 0);
        }
        float bj = b1[nt * 16 + m];
#pragma unroll
        for (int r = 0; r < 4; r++) {
            int row = quad * 4 + r;
            int col = (nt * 16 + m) ^ ((row & 7) << 2);
            unsigned short hi, lo;
            split_bf16(fmaxf(c0[r] + bj, 0.f), hi, lo);
            shp[wave][0][row][col] = (unsigned int)hi | ((unsigned int)lo << 16);
            split_bf16(fmaxf(c1[r] + bj, 0.f), hi, lo);
            shp[wave][1][row][col] = (unsigned int)hi | ((unsigned int)lo << 16);
        }
        __syncthreads();
    }
    // issue stage-2 nt=0 staging early (hides under transpose reads)
    stage_slice<4>(w2h, w2l, 0, ldsW[0], wave, lane);
#pragma unroll
    for (int s = 0; s < 2; s++)
#pragma unroll
        for (int ks = 0; ks < 4; ks++) {
            const unsigned int* rowp = &shp[wave][s][m][0];
            int base = ks * 32 + quad * 8;
            uint4 wa = *(const uint4*)&rowp[base ^ fxm];
            uint4 wb = *(const uint4*)&rowp[(base + 4) ^ fxm];
            union { unsigned int u[4]; bf16x8 v; } ch, cl;
            ch.u[0] = __builtin_amdgcn_perm(wa.y, wa.x, 0x05040100u);
            ch.u[1] = __builtin_amdgcn_perm(wa.w, wa.z, 0x05040100u);
            ch.u[2] = __builtin_amdgcn_perm(wb.y, wb.x, 0x05040100u);
            ch.u[3] = __builtin_amdgcn_perm(wb.w, wb.z, 0x05040100u);
            cl.u[0] = __builtin_amdgcn_perm(wa.y, wa.x, 0x07060302u);
            cl.u[1] = __builtin_amdgcn_perm(wa.w, wa.z, 0x07060302u);
            cl.u[2] = __builtin_amdgcn_perm(wb.y, wb.x, 0x07060302u);
            cl.u[3] = __builtin_amdgcn_perm(wb.w, wb.z, 0x07060302u);
            a2h[s][ks] = ch.v;
            a2l[s][ks] = cl.v;
        }
    __syncthreads();

    // ================= stage 2 =====================
#pragma unroll 1
    for (int nt = 0; nt < 8; nt++) {
        int cur = nt & 1;
        if (nt < 7) stage_slice<4>(w2h, w2l, nt + 1, ldsW[cur ^ 1], wave, lane);
        bf16x8 bh[4], bl[4];
#pragma unroll
        for (int ks = 0; ks < 4; ks++) {
            bh[ks] = *(const bf16x8*)&ldsW[cur][(ks * 64 + lane) * 8];
            bl[ks] = *(const bf16x8*)&ldsW[cur][2048 + (ks * 64 + lane) * 8];
        }
        f32x4 c0 = {0.f, 0.f, 0.f, 0.f};
        f32x4 c1 = {0.f, 0.f, 0.f, 0.f};
#pragma unroll
        for (int ks = 0; ks < 4; ks++) {
            c0 = __builtin_amdgcn_mfma_f32_16x16x32_bf16(a2h[0][ks], bh[ks], c0, 0, 0, 0);
            c1 = __builtin_amdgcn_mfma_f32_16x16x32_bf16(a2h[1][ks], bh[ks], c1, 0, 0, 0);
            c0 = __builtin_amdgcn_mfma_f32_16x16x32_bf16(a2l[0][ks], bh[ks], c0, 0, 0, 0);
            c1 = __builtin_amdgcn_mfma_f32_16x16x32_bf16(a2l[1][ks], bh[ks], c1, 0, 0, 0);
            c0 = __builtin_amdgcn_mfma_f32_16x16x32_bf16(a2h[0][ks], bl[ks], c0, 0, 0, 0);
            c1 = __builtin_amdgcn_mfma_f32_16x16x32_bf16(a2h[1][ks], bl[ks], c1, 0, 0, 0);
        }
        float bj = b2[nt * 16 + m];
#pragma unroll
        for (int r = 0; r < 4; r++) {
            int row = quad * 4 + r;
            int col = (nt * 16 + m) ^ ((row & 7) << 2);
            unsigned short hi, lo;
            split_bf16(fmaxf(c0[r] + bj, 0.f), hi, lo);
            shp[wave][0][row][col] = (unsigned int)hi | ((unsigned int)lo << 16);
            split_bf16(fmaxf(c1[r] + bj, 0.f), hi, lo);
            shp[wave][1][row][col] = (unsigned int)hi | ((unsigned int)lo << 16);
        }
        __syncthreads();
    }
    // issue stage-3 nt=0 staging early
    stage_slice<4>(w3h, w3l, 0, ldsW[0], wave, lane);
#pragma unroll
    for (int s = 0; s < 2; s++)
#pragma unroll
        for (int ks = 0; ks < 4; ks++) {
            const unsigned int* rowp = &shp[wave][s][m][0];
            int base = ks * 32 + quad * 8;
            uint4 wa = *(const uint4*)&rowp[base ^ fxm];
            uint4 wb = *(const uint4*)&rowp[(base + 4) ^ fxm];
            union { unsigned int u[4]; bf16x8 v; } ch, cl;
            ch.u[0] = __builtin_amdgcn_perm(wa.y, wa.x, 0x05040100u);
            ch.u[1] = __builtin_amdgcn_perm(wa.w, wa.z, 0x05040100u);
            ch.u[2] = __builtin_amdgcn_perm(wb.y, wb.x, 0x05040100u);
            ch.u[3] = __builtin_amdgcn_perm(wb.w, wb.z, 0x05040100u);
            cl.u[0] = __builtin_amdgcn_perm(wa.y, wa.x, 0x07060302u);
            cl.u[1] = __builtin_amdgcn_perm(wa.w, wa.z, 0x07060302u);
            cl.u[2] = __builtin_amdgcn_perm(wb.y, wb.x, 0x07060302u);
            cl.u[3] = __builtin_amdgcn_perm(wb.w, wb.z, 0x07060302u);
            a2h[s][ks] = ch.v;
            a2l[s][ks] = cl.v;
        }
    __syncthreads();

    // ================= stage 3 (epilogue writes folded per nt) ==============
#pragma unroll 1
    for (int nt = 0; nt < 8; nt++) {
        int cur = nt & 1;
        if (nt < 7) stage_slice<4>(w3h, w3l, nt + 1, ldsW[cur ^ 1], wave, lane);
        bf16x8 bh[4], bl[4];
#pragma unroll
        for (int ks = 0; ks < 4; ks++) {
            bh[ks] = *(const bf16x8*)&ldsW[cur][(ks * 64 + lane) * 8];
            bl[ks] = *(const bf16x8*)&ldsW[cur][2048 + (ks * 64 + lane) * 8];
        }
        f32x4 c0 = {0.f, 0.f, 0.f, 0.f};
        f32x4 c1 = {0.f, 0.f, 0.f, 0.f};
#pragma unroll
        for (int ks = 0; ks < 4; ks++) {
            c0 = __builtin_amdgcn_mfma_f32_16x16x32_bf16(a2h[0][ks], bh[ks], c0, 0, 0, 0);
            c1 = __builtin_amdgcn_mfma_f32_16x16x32_bf16(a2h[1][ks], bh[ks], c1, 0, 0, 0);
            c0 = __builtin_amdgcn_mfma_f32_16x16x32_bf16(a2l[0][ks], bh[ks], c0, 0, 0, 0);
            c1 = __builtin_amdgcn_mfma_f32_16x16x32_bf16(a2l[1][ks], bh[ks], c1, 0, 0, 0);
            c0 = __builtin_amdgcn_mfma_f32_16x16x32_bf16(a2h[0][ks], bl[ks], c0, 0, 0, 0);
            c1 = __builtin_amdgcn_mfma_f32_16x16x32_bf16(a2h[1][ks], bl[ks], c1, 0, 0, 0);
        }
        float bj = b3[nt * 16 + m];
        if (POOL) {
            float* shf0 = (float*)&shp[wave][0][0][0];
            float* shf1 = (float*)&shp[wave][1][0][0];
#pragma unroll
            for (int r = 0; r < 4; r++) {
                int row = quad * 4 + r;
                int col = (nt * 16 + m) ^ ((row & 7) << 2);
                shf0[row * 128 + col] = fmaxf(c0[r] + bj, 0.f);
                shf1[row * 128 + col] = fmaxf(c1[r] + bj, 0.f);
            }
        } else {
            unsigned short* t0 = (unsigned short*)&shp[wave][0][0][0];
            unsigned short* t1 = (unsigned short*)&shp[wave][1][0][0];
#pragma unroll
            for (int r = 0; r < 4; r++) {
                int row = quad * 4 + r;
                int hh = nt * 16 + m;                  // feature halfword idx
                int w2 = (hh >> 1) ^ ((row & 7) << 2); // swizzled word
                t0[row * 256 + w2 * 2 + (hh & 1)] = bf16_hi(fmaxf(c0[r] + bj, 0.f));
                t1[row * 256 + w2 * 2 + (hh & 1)] = bf16_hi(fmaxf(c1[r] + bj, 0.f));
            }
        }
        __syncthreads();
    }

    if (POOL) {
        // ---- fused mean-pool epilogue per s-half (per-wave private) ----
#pragma unroll
        for (int h = 0; h < 2; h++) {
            float* shf = (float*)&shp[wave][h][0][0];
            int c0i = lane * 2;
            float run0 = 0.f, run1 = 0.f;
            int gp = -1;
            for (int rrow = 0; rrow < 16; rrow++) {
                int node = nodeBase + h * 16 + rrow;
                if (node >= NN) break;
                int g = batch[node];
                float2 xv = *(const float2*)&shf[rrow * 128 + (c0i ^ ((rrow & 7) << 2))];
                if (g != gp) {
                    if (gp >= 0) {
                        atomicAdd(&pooled[(size_t)gp * HD + c0i + 0], run0);
                        atomicAdd(&pooled[(size_t)gp * HD + c0i + 1], run1);
                    }
                    run0 = xv.x; run1 = xv.y; gp = g;
                } else {
                    run0 += xv.x; run1 += xv.y;
                }
            }
            if (gp >= 0) {
                atomicAdd(&pooled[(size_t)gp * HD + c0i + 0], run0);
                atomicAdd(&pooled[(size_t)gp * HD + c0i + 1], run1);
            }
        }
    } else {
        // ---- coalesced bf16 row stores for both s-halves ----
#pragma unroll
        for (int s = 0; s < 2; s++) {
            unsigned short* sh16 = (unsigned short*)&shp[wave][s][0][0];  // [16][256]
#pragma unroll
            for (int io = 0; io < 4; io++) {
                int row16 = io * 4 + quad;
                int wbase = (m * 4) ^ ((row16 & 7) << 2);
                int n2 = nodeBase + s * 16 + row16;
                bf16x8 v = *(const bf16x8*)&sh16[row16 * 256 + wbase * 2];
                if (n2 < NN) *(bf16x8*)&out[(size_t)n2 * HD + m * 8] = v;
            }
        }
    }
}

// ---------------------------------------------------------------------------
// Classifier head: one block (128 threads) per graph.
// Graph node counts via binary search on the SORTED batch array.
// ---------------------------------------------------------------------------
__device__ inline int lb_batch(const int* __restrict__ batch, int key) {
    int lo = 0, hi = NN;
    while (lo < hi) {
        int mid = (lo + hi) >> 1;
        if (batch[mid] < key) lo = mid + 1; else hi = mid;
    }
    return lo;
}

__launch_bounds__(128)
__global__ void head(const float* __restrict__ pooled, const int* __restrict__ batch,
                     const float* __restrict__ fc0_w, const float* __restrict__ fc0_b,
                     const float* __restrict__ fc1_w, const float* __restrict__ fc1_b,
                     const float* __restrict__ out_w, const float* __restrict__ out_b,
                     float* __restrict__ out) {
    int g = blockIdx.x;
    int j = threadIdx.x;
    __shared__ float s0[HD];
    __shared__ float s1[HD];
    int c = lb_batch(batch, g + 1) - lb_batch(batch, g);
    float cf = (float)(c > 1 ? c : 1);
    s0[j] = pooled[(size_t)g * HD + j] / cf;
    __syncthreads();

    float acc = fc0_b[j];
    for (int k = 0; k < HD; k += 4) {
        float4 hv = *(const float4*)&s0[k];
        acc = fmaf(hv.x, fc0_w[(k + 0) * HD + j], acc);
        acc = fmaf(hv.y, fc0_w[(k + 1) * HD + j], acc);
        acc = fmaf(hv.z, fc0_w[(k + 2) * HD + j], acc);
        acc = fmaf(hv.w, fc0_w[(k + 3) * HD + j], acc);
    }
    s1[j] = fmaxf(acc, 0.0f);
    __syncthreads();

    acc = fc1_b[j];
    for (int k = 0; k < HD; k += 4) {
        float4 hv = *(const float4*)&s1[k];
        acc = fmaf(hv.x, fc1_w[(k + 0) * HD + j], acc);
        acc = fmaf(hv.y, fc1_w[(k + 1) * HD + j], acc);
        acc = fmaf(hv.z, fc1_w[(k + 2) * HD + j], acc);
        acc = fmaf(hv.w, fc1_w[(k + 3) * HD + j], acc);
    }
    float v = fmaxf(acc, 0.0f);

    float p0 = v * out_w[j * 2 + 0];
    float p1 = v * out_w[j * 2 + 1];
    __syncthreads();
    s0[j] = p0;
    s1[j] = p1;
    __syncthreads();
    for (int off = 64; off >= 1; off >>= 1) {
        if (j < off) {
            s0[j] += s0[j + off];
            s1[j] += s1[j + off];
        }
        __syncthreads();
    }
    if (j == 0) {
        out[(size_t)g * 2 + 0] = s0[0] + out_b[0];
        out[(size_t)g * 2 + 1] = s1[0] + out_b[1];
    }
}

// ---------------------------------------------------------------------------
extern "C" void kernel_launch(void* const* d_in, const int* in_sizes, int n_in,
                              void* d_out, int out_size, void* d_ws, size_t ws_size,
                              hipStream_t stream) {
    const float* x     = (const float*)d_in[0];
    const int*   ei    = (const int*)d_in[1];
    const int*   batch = (const int*)d_in[2];
    const float* cw[3][6];
    for (int i = 0; i < 3; i++)
        for (int k = 0; k < 6; k++) cw[i][k] = (const float*)d_in[3 + 6 * i + k];
    const float* fc0_w = (const float*)d_in[21];
    const float* fc0_b = (const float*)d_in[22];
    const float* fc1_w = (const float*)d_in[23];
    const float* fc1_b = (const float*)d_in[24];
    const float* out_w = (const float*)d_in[25];
    const float* out_b = (const float*)d_in[26];
    float* out = (float*)d_out;

    char* ws = (char*)d_ws;
    size_t off = 0;
    auto carve = [&](size_t bytes) {
        void* p = ws + off;
        off += (bytes + 255) & ~(size_t)255;
        return p;
    };
    // cnt_node and pooled contiguous (zeroed together by init_zero)
    int*   cnt_node = (int*)carve((size_t)NN * 4);
    float* pooled   = (float*)carve((size_t)GG * HD * 4);
    int*   bucket   = (int*)carve((size_t)NN * CAP * 4);
    unsigned short* hA = (unsigned short*)carve((size_t)NP * HD * 2);
    unsigned short* hB = (unsigned short*)carve((size_t)NP * HD * 2);
    unsigned short* wHi[9];
    unsigned short* wLo[9];
    int wK[9] = {F_IN, HD, HD, HD, HD, HD, HD, HD, HD};
    for (int i = 0; i < 9; i++) {
        wHi[i] = (unsigned short*)carve((size_t)wK[i] * HD * 2);
        wLo[i] = (unsigned short*)carve((size_t)wK[i] * HD * 2);
    }
    (void)ws_size;

    init_zero<<<(GG * HD + 255) / 256, 256, 0, stream>>>(cnt_node, pooled);
    build_graph<<<(EE + 255) / 256, 256, 0, stream>>>(ei, cnt_node, bucket);

    PrepArgs pa;
    for (int l = 0; l < 3; l++)
        for (int s = 0; s < 3; s++) {
            int i = l * 3 + s;
            pa.d[i].src = cw[l][2 * s];
            pa.d[i].dhi = wHi[i];
            pa.d[i].dlo = wLo[i];
            pa.d[i].K = wK[i];
        }
    prep_weights<<<dim3(16, 9), 256, 0, stream>>>(pa);

    const int blocks = NP / 128;  // 1172

    // ---- GIN layer 0 (K=32, fp32 in): x -> hA (bf16) ----
    gin_layer<F_IN, false, false><<<blocks, 256, 0, stream>>>(x, cnt_node, bucket,
        wHi[0], wLo[0], cw[0][1], wHi[1], wLo[1], cw[0][3], wHi[2], wLo[2], cw[0][5],
        hA, batch, pooled);
    // ---- GIN layer 1 (bf16 in): hA -> hB (bf16) ----
    gin_layer<HD, true, false><<<blocks, 256, 0, stream>>>(hA, cnt_node, bucket,
        wHi[3], wLo[3], cw[1][1], wHi[4], wLo[4], cw[1][3], wHi[5], wLo[5], cw[1][5],
        hB, batch, pooled);
    // ---- GIN layer 2 (bf16 in): hB -> pooled (fused mean-pool sum) ----
    gin_layer<HD, true, true><<<blocks, 256, 0, stream>>>(hB, cnt_node, bucket,
        wHi[6], wLo[6], cw[2][1], wHi[7], wLo[7], cw[2][3], wHi[8], wLo[8], cw[2][5],
        nullptr, batch, pooled);

    // ---- head ----
    head<<<GG, 128, 0, stream>>>(pooled, batch, fc0_w, fc0_b, fc1_w, fc1_b, out_w, out_b, out);
}

// Round 12
// 477.244 us; speedup vs baseline: 1.1602x; 1.1602x over previous
//
#include <hip/hip_runtime.h>
#include <hip/hip_bf16.h>

// Problem constants (fixed by the reference)
#define NN 150000      // nodes
#define EE 600000      // edges
#define F_IN 32        // input node features
#define HD 128         // hidden dim
#define GG 2048        // graphs
#define CAP 28         // max degree bucket capacity (Poisson(4): P(deg>=28) ~ 4e-18)
#define NP 150016      // NN rounded up to 128-node blocks: 1172*128

typedef __attribute__((ext_vector_type(8))) short bf16x8;
typedef __attribute__((ext_vector_type(4))) float f32x4;
typedef __attribute__((ext_vector_type(4))) int i32x4;
typedef __attribute__((address_space(1))) const void g1void;
typedef __attribute__((address_space(3))) void l3void;

__device__ inline void split_bf16(float v, unsigned short& hi, unsigned short& lo) {
    __hip_bfloat16 h = __float2bfloat16(v);
    float hv = __bfloat162float(h);
    __hip_bfloat16 l = __float2bfloat16(v - hv);
    hi = *reinterpret_cast<unsigned short*>(&h);
    lo = *reinterpret_cast<unsigned short*>(&l);
}
__device__ inline unsigned short bf16_hi(float v) {
    __hip_bfloat16 h = __float2bfloat16(v);
    return *reinterpret_cast<unsigned short*>(&h);
}
__device__ inline float bf2f(unsigned short u) {
    union { unsigned int i; float f; } c;
    c.i = ((unsigned int)u) << 16;
    return c.f;
}

// ---------------------------------------------------------------------------
// Zero-init for workspace regions
// ---------------------------------------------------------------------------
__global__ void init_zero(int* __restrict__ cnt_node, float* __restrict__ pooled) {
    int i = blockIdx.x * blockDim.x + threadIdx.x;
    if (i < NN) cnt_node[i] = 0;
    if (i < GG * HD) pooled[i] = 0.f;
}

// ---------------------------------------------------------------------------
// CSR-bucket build. AoS bucket[dst*CAP+slot].
// ---------------------------------------------------------------------------
__global__ void build_graph(const int* __restrict__ ei,
                            int* __restrict__ cnt_node,
                            int* __restrict__ bucket) {
    int e = blockIdx.x * blockDim.x + threadIdx.x;
    if (e >= EE) return;
    int src = ei[e];         // edge_index[0]
    int dst = ei[EE + e];    // edge_index[1]
    int slot = atomicAdd(&cnt_node[dst], 1);
    if (slot < CAP) bucket[dst * CAP + slot] = src;
}

// ---------------------------------------------------------------------------
// Weight prep: fp32 W[K][H] -> split-bf16 packed in LANE-LINEAR fragment order
// ---------------------------------------------------------------------------
struct PrepDesc { const float* src; unsigned short* dhi; unsigned short* dlo; int K; };
struct PrepArgs { PrepDesc d[9]; };

__global__ void prep_weights(PrepArgs pa) {
    PrepDesc de = pa.d[blockIdx.y];
    int total = de.K * HD;
    int KS = de.K >> 5;
    for (int idx = blockIdx.x * blockDim.x + threadIdx.x; idx < total;
         idx += gridDim.x * blockDim.x) {
        int k = idx / HD, h = idx - (idx / HD) * HD;   // src is [K][H]
        unsigned short hi, lo;
        split_bf16(de.src[idx], hi, lo);
        int nt = h >> 4, m = h & 15;
        int ks = k >> 5, quad = (k >> 3) & 3, e = k & 7;
        int lane = quad * 16 + m;
        int pidx = ((nt * KS + ks) * 64 + lane) * 8 + e;
        de.dhi[pidx] = hi;
        de.dlo[pidx] = lo;
    }
}

// ---------------------------------------------------------------------------
// Stage one nt-slice of weights (hi+lo tables) into LDS, cooperatively
// across 4 waves via global_load_lds (wave-uniform LDS base, per-lane gsrc).
// ---------------------------------------------------------------------------
template <int KS>
__device__ inline void stage_slice(const unsigned short* __restrict__ wh,
                                   const unsigned short* __restrict__ wl,
                                   int nt, unsigned short* dst, int wave, int lane) {
    if (KS == 4) {
        const unsigned short* gh = wh + nt * 2048 + wave * 512 + lane * 8;
        const unsigned short* gl = wl + nt * 2048 + wave * 512 + lane * 8;
        __builtin_amdgcn_global_load_lds((g1void*)gh, (l3void*)(dst + wave * 512), 16, 0, 0);
        __builtin_amdgcn_global_load_lds((g1void*)gl, (l3void*)(dst + 2048 + wave * 512), 16, 0, 0);
    } else {
        if (wave < 2) {
            const unsigned short* g = (wave == 0 ? wh : wl) + nt * 512 + lane * 8;
            __builtin_amdgcn_global_load_lds((g1void*)g, (l3void*)(dst + wave * 512), 16, 0, 0);
        }
    }
}

// ---------------------------------------------------------------------------
// Fused GIN layer (R12): R10 base (LDS-staged weights, 123us/layer verified,
// WRITE 11.3MB no-spill) + three register-light chain-shortening tweaks:
//  (1) stage-1 nt=0 weight DMA hoisted above the gather (runs under it).
//  (2) both s-halves' cnt + self-rows hoisted before the gather loops
//      (removes the cnt-load latency from the head of s=1's chain).
//  (3) bf16 gather: int4 bucket-index load with 1-deep prefetch (one 16B
//      load/round issued a round ahead vs 4 scalar loads on the chain;
//      bucket rows are 112B=16B-aligned; +16B bucket pad covers overrun).
// R11's merged-s gather REVERTED (spilled: dual accumulators + 16 row regs
// pushed VGPR to 128 w/ scratch; WRITE 11->51MB).
// ---------------------------------------------------------------------------
template <int K_IN, bool BF16IN, bool POOL>
__launch_bounds__(256, 2)
__global__ void gin_layer(const void* __restrict__ hin_,
                          const int* __restrict__ cnt_node,
                          const int* __restrict__ bucket,
                          const unsigned short* __restrict__ w1h, const unsigned short* __restrict__ w1l,
                          const float* __restrict__ b1,
                          const unsigned short* __restrict__ w2h, const unsigned short* __restrict__ w2l,
                          const float* __restrict__ b2,
                          const unsigned short* __restrict__ w3h, const unsigned short* __restrict__ w3l,
                          const float* __restrict__ b3,
                          unsigned short* __restrict__ out,   // bf16 activations (non-pool)
                          const int* __restrict__ batch,
                          float* __restrict__ pooled) {
    constexpr int KS1 = K_IN / 32;
    // Per-wave, per-s swizzled transpose buffers: 4 x 2 x 16 x 128 u32 = 64 KB
    __shared__ unsigned int shp[4][2][16][128];
    // Double-buffered weight staging: 2 x 4096 hw = 16 KB
    __shared__ unsigned short ldsW[2][4096];

    const int wave = threadIdx.x >> 6;
    const int lane = threadIdx.x & 63;
    const int m = lane & 15;      // node row within a 16-set / out-feature col
    const int quad = lane >> 4;   // 0..3
    const int nodeBase = blockIdx.x * 128 + wave * 32;

    const float* hf = (const float*)hin_;
    const unsigned short* hb = (const unsigned short*)hin_;

    // (1) stage-1 nt=0 weight DMA issued BEFORE the gather: runs underneath it.
    stage_slice<KS1>(w1h, w1l, 0, ldsW[0], wave, lane);

    // (2) hoist node ids, cnts for both s-halves
    int node_s[2], cnt_s[2];
#pragma unroll
    for (int s = 0; s < 2; s++) {
        int node = nodeBase + s * 16 + m;
        node_s[s] = node < NN ? node : NN - 1;
    }
    cnt_s[0] = cnt_node[node_s[0]];
    cnt_s[1] = cnt_node[node_s[1]];
#pragma unroll
    for (int s = 0; s < 2; s++) cnt_s[s] = cnt_s[s] < CAP ? cnt_s[s] : CAP;

    // ---- fused aggregation: self + neighbors, fp32 -> split-bf16 A frags ----
    bf16x8 ah[2][KS1], al[2][KS1];
#pragma unroll
    for (int s = 0; s < 2; s++) {
        int node = node_s[s];
        float ag[KS1][8];
        if (BF16IN) {
            const unsigned short* rs = hb + (size_t)node * K_IN + quad * 8;
#pragma unroll
            for (int ks = 0; ks < KS1; ks++) {
                bf16x8 v = *(const bf16x8*)(rs + ks * 32);
#pragma unroll
                for (int e = 0; e < 8; e++) ag[ks][e] = bf2f((unsigned short)v[e]);
            }
        } else {
            const float* rs = hf + (size_t)node * K_IN + quad * 8;
#pragma unroll
            for (int ks = 0; ks < KS1; ks++) {
                float4 v0 = *(const float4*)(rs + ks * 32);
                float4 v1 = *(const float4*)(rs + ks * 32 + 4);
                ag[ks][0] = v0.x; ag[ks][1] = v0.y; ag[ks][2] = v0.z; ag[ks][3] = v0.w;
                ag[ks][4] = v1.x; ag[ks][5] = v1.y; ag[ks][6] = v1.z; ag[ks][7] = v1.w;
            }
        }
        int cnt = cnt_s[s];
        const int* b = bucket + (size_t)node * CAP;
        int i = 0;
        if (BF16IN) {
            if (cnt >= 4) {
                // (3) int4 index loads, 1-deep prefetch (pad covers overrun)
                i32x4 iv = *(const i32x4*)b;
                for (; i + 4 <= cnt; i += 4) {
                    i32x4 ivn = *(const i32x4*)(b + i + 4);
                    bf16x8 v[4][KS1];
#pragma unroll
                    for (int j = 0; j < 4; j++) {
                        const unsigned short* r = hb + (size_t)iv[j] * K_IN + quad * 8;
#pragma unroll
                        for (int ks = 0; ks < KS1; ks++)
                            v[j][ks] = *(const bf16x8*)(r + ks * 32);
                    }
#pragma unroll
                    for (int ks = 0; ks < KS1; ks++)
#pragma unroll
                        for (int e = 0; e < 8; e++) {
                            float t01 = bf2f((unsigned short)v[0][ks][e]) +
                                        bf2f((unsigned short)v[1][ks][e]);
                            float t23 = bf2f((unsigned short)v[2][ks][e]) +
                                        bf2f((unsigned short)v[3][ks][e]);
                            ag[ks][e] += t01 + t23;
                        }
                    iv = ivn;
                }
            }
            for (; i < cnt; i++) {
                const unsigned short* r = hb + (size_t)b[i] * K_IN + quad * 8;
#pragma unroll
                for (int ks = 0; ks < KS1; ks++) {
                    bf16x8 v = *(const bf16x8*)(r + ks * 32);
#pragma unroll
                    for (int e = 0; e < 8; e++) ag[ks][e] += bf2f((unsigned short)v[e]);
                }
            }
        } else {
            for (; i + 8 <= cnt; i += 8) {
                float4 v0[8], v1[8];
#pragma unroll
                for (int j = 0; j < 8; j++) {
                    const float* r = hf + (size_t)b[i + j] * K_IN + quad * 8;
                    v0[j] = *(const float4*)r;
                    v1[j] = *(const float4*)(r + 4);
                }
#pragma unroll
                for (int e = 0; e < 4; e++) {
                    float s01 = (&v0[0].x)[e] + (&v0[1].x)[e] + (&v0[4].x)[e] + (&v0[5].x)[e];
                    float s23 = (&v0[2].x)[e] + (&v0[3].x)[e] + (&v0[6].x)[e] + (&v0[7].x)[e];
                    ag[0][e] += s01 + s23;
                }
#pragma unroll
                for (int e = 0; e < 4; e++) {
                    float s01 = (&v1[0].x)[e] + (&v1[1].x)[e] + (&v1[4].x)[e] + (&v1[5].x)[e];
                    float s23 = (&v1[2].x)[e] + (&v1[3].x)[e] + (&v1[6].x)[e] + (&v1[7].x)[e];
                    ag[0][e + 4] += s01 + s23;
                }
            }
            for (; i < cnt; i++) {
                const float* r = hf + (size_t)b[i] * K_IN + quad * 8;
                float4 v0 = *(const float4*)r;
                float4 v1 = *(const float4*)(r + 4);
                ag[0][0] += v0.x; ag[0][1] += v0.y; ag[0][2] += v0.z; ag[0][3] += v0.w;
                ag[0][4] += v1.x; ag[0][5] += v1.y; ag[0][6] += v1.z; ag[0][7] += v1.w;
            }
        }
#pragma unroll
        for (int ks = 0; ks < KS1; ks++) {
            bf16x8 vh, vl;
#pragma unroll
            for (int e = 0; e < 8; e++) {
                unsigned short hi, lo;
                split_bf16(ag[ks][e], hi, lo);
                vh[e] = (short)hi;
                vl[e] = (short)lo;
            }
            ah[s][ks] = vh;
            al[s][ks] = vl;
        }
    }

    bf16x8 a2h[2][4], a2l[2][4];
    const int fxm = (m & 7) << 2;          // read-side swizzle for row m

    // ================= stage 1: LDS-staged weights, dual accumulators =======
    __syncthreads();
#pragma unroll 1
    for (int nt = 0; nt < 8; nt++) {
        int cur = nt & 1;
        if (nt < 7) stage_slice<KS1>(w1h, w1l, nt + 1, ldsW[cur ^ 1], wave, lane);
        bf16x8 bh[KS1], bl[KS1];
#pragma unroll
        for (int ks = 0; ks < KS1; ks++) {
            bh[ks] = *(const bf16x8*)&ldsW[cur][(ks * 64 + lane) * 8];
            bl[ks] = *(const bf16x8*)&ldsW[cur][KS1 * 512 + (ks * 64 + lane) * 8];
        }
        f32x4 c0 = {0.f, 0.f, 0.f, 0.f};
        f32x4 c1 = {0.f, 0.f, 0.f, 0.f};
#pragma unroll
        for (int ks = 0; ks < KS1; ks++) {
            c0 = __builtin_amdgcn_mfma_f32_16x16x32_bf16(ah[0][ks], bh[ks], c0, 0, 0, 0);
            c1 = __builtin_amdgcn_mfma_f32_16x16x32_bf16(ah[1][ks], bh[ks], c1, 0, 0, 0);
            c0 = __builtin_amdgcn_mfma_f32_16x16x32_bf16(al[0][ks], bh[ks], c0, 0, 0, 0);
            c1 = __builtin_amdgcn_mfma_f32_16x16x32_bf16(al[1][ks], bh[ks], c1, 0, 0, 0);
            c0 = __builtin_amdgcn_mfma_f32_16x16x32_bf16(ah[0][ks], bl[ks], c0, 0, 0, 0);
            c1 = __builtin_amdgcn_mfma_f32_16x16x32_bf16(ah[1][ks], bl[ks], c1, 0, 0, 0);
        }
        float bj = b1[nt * 16 + m];
#pragma unroll
        for (int r = 0; r < 4; r++) {
            int row = quad * 4 + r;
            int col = (nt * 16 + m) ^ ((row & 7) << 2);
            unsigned short hi, lo;
            split_bf16(fmaxf(c0[r] + bj, 0.f), hi, lo);
            shp[wave][0][row][col] = (unsigned int)hi | ((unsigned int)lo << 16);
            split_bf16(fmaxf(c1[r] + bj, 0.f), hi, lo);
            shp[wave][1][row][col] = (unsigned int)hi | ((unsigned int)lo << 16);
        }
        __syncthreads();
    }
    // issue stage-2 nt=0 staging early (hides under transpose reads)
    stage_slice<4>(w2h, w2l, 0, ldsW[0], wave, lane);
#pragma unroll
    for (int s = 0; s < 2; s++)
#pragma unroll
        for (int ks = 0; ks < 4; ks++) {
            const unsigned int* rowp = &shp[wave][s][m][0];
            int base = ks * 32 + quad * 8;
            uint4 wa = *(const uint4*)&rowp[base ^ fxm];
            uint4 wb = *(const uint4*)&rowp[(base + 4) ^ fxm];
            union { unsigned int u[4]; bf16x8 v; } ch, cl;
            ch.u[0] = __builtin_amdgcn_perm(wa.y, wa.x, 0x05040100u);
            ch.u[1] = __builtin_amdgcn_perm(wa.w, wa.z, 0x05040100u);
            ch.u[2] = __builtin_amdgcn_perm(wb.y, wb.x, 0x05040100u);
            ch.u[3] = __builtin_amdgcn_perm(wb.w, wb.z, 0x05040100u);
            cl.u[0] = __builtin_amdgcn_perm(wa.y, wa.x, 0x07060302u);
            cl.u[1] = __builtin_amdgcn_perm(wa.w, wa.z, 0x07060302u);
            cl.u[2] = __builtin_amdgcn_perm(wb.y, wb.x, 0x07060302u);
            cl.u[3] = __builtin_amdgcn_perm(wb.w, wb.z, 0x07060302u);
            a2h[s][ks] = ch.v;
            a2l[s][ks] = cl.v;
        }
    __syncthreads();

    // ================= stage 2 =====================
#pragma unroll 1
    for (int nt = 0; nt < 8; nt++) {
        int cur = nt & 1;
        if (nt < 7) stage_slice<4>(w2h, w2l, nt + 1, ldsW[cur ^ 1], wave, lane);
        bf16x8 bh[4], bl[4];
#pragma unroll
        for (int ks = 0; ks < 4; ks++) {
            bh[ks] = *(const bf16x8*)&ldsW[cur][(ks * 64 + lane) * 8];
            bl[ks] = *(const bf16x8*)&ldsW[cur][2048 + (ks * 64 + lane) * 8];
        }
        f32x4 c0 = {0.f, 0.f, 0.f, 0.f};
        f32x4 c1 = {0.f, 0.f, 0.f, 0.f};
#pragma unroll
        for (int ks = 0; ks < 4; ks++) {
            c0 = __builtin_amdgcn_mfma_f32_16x16x32_bf16(a2h[0][ks], bh[ks], c0, 0, 0, 0);
            c1 = __builtin_amdgcn_mfma_f32_16x16x32_bf16(a2h[1][ks], bh[ks], c1, 0, 0, 0);
            c0 = __builtin_amdgcn_mfma_f32_16x16x32_bf16(a2l[0][ks], bh[ks], c0, 0, 0, 0);
            c1 = __builtin_amdgcn_mfma_f32_16x16x32_bf16(a2l[1][ks], bh[ks], c1, 0, 0, 0);
            c0 = __builtin_amdgcn_mfma_f32_16x16x32_bf16(a2h[0][ks], bl[ks], c0, 0, 0, 0);
            c1 = __builtin_amdgcn_mfma_f32_16x16x32_bf16(a2h[1][ks], bl[ks], c1, 0, 0, 0);
        }
        float bj = b2[nt * 16 + m];
#pragma unroll
        for (int r = 0; r < 4; r++) {
            int row = quad * 4 + r;
            int col = (nt * 16 + m) ^ ((row & 7) << 2);
            unsigned short hi, lo;
            split_bf16(fmaxf(c0[r] + bj, 0.f), hi, lo);
            shp[wave][0][row][col] = (unsigned int)hi | ((unsigned int)lo << 16);
            split_bf16(fmaxf(c1[r] + bj, 0.f), hi, lo);
            shp[wave][1][row][col] = (unsigned int)hi | ((unsigned int)lo << 16);
        }
        __syncthreads();
    }
    // issue stage-3 nt=0 staging early
    stage_slice<4>(w3h, w3l, 0, ldsW[0], wave, lane);
#pragma unroll
    for (int s = 0; s < 2; s++)
#pragma unroll
        for (int ks = 0; ks < 4; ks++) {
            const unsigned int* rowp = &shp[wave][s][m][0];
            int base = ks * 32 + quad * 8;
            uint4 wa = *(const uint4*)&rowp[base ^ fxm];
            uint4 wb = *(const uint4*)&rowp[(base + 4) ^ fxm];
            union { unsigned int u[4]; bf16x8 v; } ch, cl;
            ch.u[0] = __builtin_amdgcn_perm(wa.y, wa.x, 0x05040100u);
            ch.u[1] = __builtin_amdgcn_perm(wa.w, wa.z, 0x05040100u);
            ch.u[2] = __builtin_amdgcn_perm(wb.y, wb.x, 0x05040100u);
            ch.u[3] = __builtin_amdgcn_perm(wb.w, wb.z, 0x05040100u);
            cl.u[0] = __builtin_amdgcn_perm(wa.y, wa.x, 0x07060302u);
            cl.u[1] = __builtin_amdgcn_perm(wa.w, wa.z, 0x07060302u);
            cl.u[2] = __builtin_amdgcn_perm(wb.y, wb.x, 0x07060302u);
            cl.u[3] = __builtin_amdgcn_perm(wb.w, wb.z, 0x07060302u);
            a2h[s][ks] = ch.v;
            a2l[s][ks] = cl.v;
        }
    __syncthreads();

    // ================= stage 3 (epilogue writes folded per nt) ==============
#pragma unroll 1
    for (int nt = 0; nt < 8; nt++) {
        int cur = nt & 1;
        if (nt < 7) stage_slice<4>(w3h, w3l, nt + 1, ldsW[cur ^ 1], wave, lane);
        bf16x8 bh[4], bl[4];
#pragma unroll
        for (int ks = 0; ks < 4; ks++) {
            bh[ks] = *(const bf16x8*)&ldsW[cur][(ks * 64 + lane) * 8];
            bl[ks] = *(const bf16x8*)&ldsW[cur][2048 + (ks * 64 + lane) * 8];
        }
        f32x4 c0 = {0.f, 0.f, 0.f, 0.f};
        f32x4 c1 = {0.f, 0.f, 0.f, 0.f};
#pragma unroll
        for (int ks = 0; ks < 4; ks++) {
            c0 = __builtin_amdgcn_mfma_f32_16x16x32_bf16(a2h[0][ks], bh[ks], c0, 0, 0, 0);
            c1 = __builtin_amdgcn_mfma_f32_16x16x32_bf16(a2h[1][ks], bh[ks], c1, 0, 0, 0);
            c0 = __builtin_amdgcn_mfma_f32_16x16x32_bf16(a2l[0][ks], bh[ks], c0, 0, 0, 0);
            c1 = __builtin_amdgcn_mfma_f32_16x16x32_bf16(a2l[1][ks], bh[ks], c1, 0, 0, 0);
            c0 = __builtin_amdgcn_mfma_f32_16x16x32_bf16(a2h[0][ks], bl[ks], c0, 0, 0, 0);
            c1 = __builtin_amdgcn_mfma_f32_16x16x32_bf16(a2h[1][ks], bl[ks], c1, 0, 0, 0);
        }
        float bj = b3[nt * 16 + m];
        if (POOL) {
            float* shf0 = (float*)&shp[wave][0][0][0];
            float* shf1 = (float*)&shp[wave][1][0][0];
#pragma unroll
            for (int r = 0; r < 4; r++) {
                int row = quad * 4 + r;
                int col = (nt * 16 + m) ^ ((row & 7) << 2);
                shf0[row * 128 + col] = fmaxf(c0[r] + bj, 0.f);
                shf1[row * 128 + col] = fmaxf(c1[r] + bj, 0.f);
            }
        } else {
            unsigned short* t0 = (unsigned short*)&shp[wave][0][0][0];
            unsigned short* t1 = (unsigned short*)&shp[wave][1][0][0];
#pragma unroll
            for (int r = 0; r < 4; r++) {
                int row = quad * 4 + r;
                int hh = nt * 16 + m;                  // feature halfword idx
                int w2 = (hh >> 1) ^ ((row & 7) << 2); // swizzled word
                t0[row * 256 + w2 * 2 + (hh & 1)] = bf16_hi(fmaxf(c0[r] + bj, 0.f));
                t1[row * 256 + w2 * 2 + (hh & 1)] = bf16_hi(fmaxf(c1[r] + bj, 0.f));
            }
        }
        __syncthreads();
    }

    if (POOL) {
        // ---- fused mean-pool epilogue per s-half (per-wave private) ----
#pragma unroll
        for (int h = 0; h < 2; h++) {
            float* shf = (float*)&shp[wave][h][0][0];
            int c0i = lane * 2;
            float run0 = 0.f, run1 = 0.f;
            int gp = -1;
            for (int rrow = 0; rrow < 16; rrow++) {
                int node = nodeBase + h * 16 + rrow;
                if (node >= NN) break;
                int g = batch[node];
                float2 xv = *(const float2*)&shf[rrow * 128 + (c0i ^ ((rrow & 7) << 2))];
                if (g != gp) {
                    if (gp >= 0) {
                        atomicAdd(&pooled[(size_t)gp * HD + c0i + 0], run0);
                        atomicAdd(&pooled[(size_t)gp * HD + c0i + 1], run1);
                    }
                    run0 = xv.x; run1 = xv.y; gp = g;
                } else {
                    run0 += xv.x; run1 += xv.y;
                }
            }
            if (gp >= 0) {
                atomicAdd(&pooled[(size_t)gp * HD + c0i + 0], run0);
                atomicAdd(&pooled[(size_t)gp * HD + c0i + 1], run1);
            }
        }
    } else {
        // ---- coalesced bf16 row stores for both s-halves ----
#pragma unroll
        for (int s = 0; s < 2; s++) {
            unsigned short* sh16 = (unsigned short*)&shp[wave][s][0][0];  // [16][256]
#pragma unroll
            for (int io = 0; io < 4; io++) {
                int row16 = io * 4 + quad;
                int wbase = (m * 4) ^ ((row16 & 7) << 2);
                int n2 = nodeBase + s * 16 + row16;
                bf16x8 v = *(const bf16x8*)&sh16[row16 * 256 + wbase * 2];
                if (n2 < NN) *(bf16x8*)&out[(size_t)n2 * HD + m * 8] = v;
            }
        }
    }
}

// ---------------------------------------------------------------------------
// Classifier head: one block (128 threads) per graph.
// Graph node counts via binary search on the SORTED batch array.
// ---------------------------------------------------------------------------
__device__ inline int lb_batch(const int* __restrict__ batch, int key) {
    int lo = 0, hi = NN;
    while (lo < hi) {
        int mid = (lo + hi) >> 1;
        if (batch[mid] < key) lo = mid + 1; else hi = mid;
    }
    return lo;
}

__launch_bounds__(128)
__global__ void head(const float* __restrict__ pooled, const int* __restrict__ batch,
                     const float* __restrict__ fc0_w, const float* __restrict__ fc0_b,
                     const float* __restrict__ fc1_w, const float* __restrict__ fc1_b,
                     const float* __restrict__ out_w, const float* __restrict__ out_b,
                     float* __restrict__ out) {
    int g = blockIdx.x;
    int j = threadIdx.x;
    __shared__ float s0[HD];
    __shared__ float s1[HD];
    int c = lb_batch(batch, g + 1) - lb_batch(batch, g);
    float cf = (float)(c > 1 ? c : 1);
    s0[j] = pooled[(size_t)g * HD + j] / cf;
    __syncthreads();

    float acc = fc0_b[j];
    for (int k = 0; k < HD; k += 4) {
        float4 hv = *(const float4*)&s0[k];
        acc = fmaf(hv.x, fc0_w[(k + 0) * HD + j], acc);
        acc = fmaf(hv.y, fc0_w[(k + 1) * HD + j], acc);
        acc = fmaf(hv.z, fc0_w[(k + 2) * HD + j], acc);
        acc = fmaf(hv.w, fc0_w[(k + 3) * HD + j], acc);
    }
    s1[j] = fmaxf(acc, 0.0f);
    __syncthreads();

    acc = fc1_b[j];
    for (int k = 0; k < HD; k += 4) {
        float4 hv = *(const float4*)&s1[k];
        acc = fmaf(hv.x, fc1_w[(k + 0) * HD + j], acc);
        acc = fmaf(hv.y, fc1_w[(k + 1) * HD + j], acc);
        acc = fmaf(hv.z, fc1_w[(k + 2) * HD + j], acc);
        acc = fmaf(hv.w, fc1_w[(k + 3) * HD + j], acc);
    }
    float v = fmaxf(acc, 0.0f);

    float p0 = v * out_w[j * 2 + 0];
    float p1 = v * out_w[j * 2 + 1];
    __syncthreads();
    s0[j] = p0;
    s1[j] = p1;
    __syncthreads();
    for (int off = 64; off >= 1; off >>= 1) {
        if (j < off) {
            s0[j] += s0[j + off];
            s1[j] += s1[j + off];
        }
        __syncthreads();
    }
    if (j == 0) {
        out[(size_t)g * 2 + 0] = s0[0] + out_b[0];
        out[(size_t)g * 2 + 1] = s1[0] + out_b[1];
    }
}

// ---------------------------------------------------------------------------
extern "C" void kernel_launch(void* const* d_in, const int* in_sizes, int n_in,
                              void* d_out, int out_size, void* d_ws, size_t ws_size,
                              hipStream_t stream) {
    const float* x     = (const float*)d_in[0];
    const int*   ei    = (const int*)d_in[1];
    const int*   batch = (const int*)d_in[2];
    const float* cw[3][6];
    for (int i = 0; i < 3; i++)
        for (int k = 0; k < 6; k++) cw[i][k] = (const float*)d_in[3 + 6 * i + k];
    const float* fc0_w = (const float*)d_in[21];
    const float* fc0_b = (const float*)d_in[22];
    const float* fc1_w = (const float*)d_in[23];
    const float* fc1_b = (const float*)d_in[24];
    const float* out_w = (const float*)d_in[25];
    const float* out_b = (const float*)d_in[26];
    float* out = (float*)d_out;

    char* ws = (char*)d_ws;
    size_t off = 0;
    auto carve = [&](size_t bytes) {
        void* p = ws + off;
        off += (bytes + 255) & ~(size_t)255;
        return p;
    };
    // cnt_node and pooled contiguous (zeroed together by init_zero)
    int*   cnt_node = (int*)carve((size_t)NN * 4);
    float* pooled   = (float*)carve((size_t)GG * HD * 4);
    int*   bucket   = (int*)carve((size_t)NN * CAP * 4 + 16);  // +16B: idx-prefetch overrun pad
    unsigned short* hA = (unsigned short*)carve((size_t)NP * HD * 2);
    unsigned short* hB = (unsigned short*)carve((size_t)NP * HD * 2);
    unsigned short* wHi[9];
    unsigned short* wLo[9];
    int wK[9] = {F_IN, HD, HD, HD, HD, HD, HD, HD, HD};
    for (int i = 0; i < 9; i++) {
        wHi[i] = (unsigned short*)carve((size_t)wK[i] * HD * 2);
        wLo[i] = (unsigned short*)carve((size_t)wK[i] * HD * 2);
    }
    (void)ws_size;

    init_zero<<<(GG * HD + 255) / 256, 256, 0, stream>>>(cnt_node, pooled);
    build_graph<<<(EE + 255) / 256, 256, 0, stream>>>(ei, cnt_node, bucket);

    PrepArgs pa;
    for (int l = 0; l < 3; l++)
        for (int s = 0; s < 3; s++) {
            int i = l * 3 + s;
            pa.d[i].src = cw[l][2 * s];
            pa.d[i].dhi = wHi[i];
            pa.d[i].dlo = wLo[i];
            pa.d[i].K = wK[i];
        }
    prep_weights<<<dim3(16, 9), 256, 0, stream>>>(pa);

    const int blocks = NP / 128;  // 1172

    // ---- GIN layer 0 (K=32, fp32 in): x -> hA (bf16) ----
    gin_layer<F_IN, false, false><<<blocks, 256, 0, stream>>>(x, cnt_node, bucket,
        wHi[0], wLo[0], cw[0][1], wHi[1], wLo[1], cw[0][3], wHi[2], wLo[2], cw[0][5],
        hA, batch, pooled);
    // ---- GIN layer 1 (bf16 in): hA -> hB (bf16) ----
    gin_layer<HD, true, false><<<blocks, 256, 0, stream>>>(hA, cnt_node, bucket,
        wHi[3], wLo[3], cw[1][1], wHi[4], wLo[4], cw[1][3], wHi[5], wLo[5], cw[1][5],
        hB, batch, pooled);
    // ---- GIN layer 2 (bf16 in): hB -> pooled (fused mean-pool sum) ----
    gin_layer<HD, true, true><<<blocks, 256, 0, stream>>>(hB, cnt_node, bucket,
        wHi[6], wLo[6], cw[2][1], wHi[7], wLo[7], cw[2][3], wHi[8], wLo[8], cw[2][5],
        nullptr, batch, pooled);

    // ---- head ----
    head<<<GG, 128, 0, stream>>>(pooled, batch, fc0_w, fc0_b, fc1_w, fc1_b, out_w, out_b, out);
}

// Round 13
// 445.719 us; speedup vs baseline: 1.2422x; 1.0707x over previous
//
#include <hip/hip_runtime.h>
#include <hip/hip_bf16.h>

// Problem constants (fixed by the reference)
#define NN 150000      // nodes
#define EE 600000      // edges
#define F_IN 32        // input node features
#define HD 128         // hidden dim
#define GG 2048        // graphs
#define CAP 28         // max degree bucket capacity (Poisson(4): P(deg>=28) ~ 4e-18)
#define NP 150016      // NN rounded up to 128-node blocks: 1172*128

typedef __attribute__((ext_vector_type(8))) short bf16x8;
typedef __attribute__((ext_vector_type(4))) float f32x4;
typedef __attribute__((address_space(1))) const void g1void;
typedef __attribute__((address_space(3))) void l3void;

__device__ inline void split_bf16(float v, unsigned short& hi, unsigned short& lo) {
    __hip_bfloat16 h = __float2bfloat16(v);
    float hv = __bfloat162float(h);
    __hip_bfloat16 l = __float2bfloat16(v - hv);
    hi = *reinterpret_cast<unsigned short*>(&h);
    lo = *reinterpret_cast<unsigned short*>(&l);
}
__device__ inline unsigned short bf16_hi(float v) {
    __hip_bfloat16 h = __float2bfloat16(v);
    return *reinterpret_cast<unsigned short*>(&h);
}
__device__ inline float bf2f(unsigned short u) {
    union { unsigned int i; float f; } c;
    c.i = ((unsigned int)u) << 16;
    return c.f;
}

// ---------------------------------------------------------------------------
// Zero-init for workspace regions
// ---------------------------------------------------------------------------
__global__ void init_zero(int* __restrict__ cnt_node, float* __restrict__ pooled) {
    int i = blockIdx.x * blockDim.x + threadIdx.x;
    if (i < NN) cnt_node[i] = 0;
    if (i < GG * HD) pooled[i] = 0.f;
}

// ---------------------------------------------------------------------------
// CSR-bucket build. AoS bucket[dst*CAP+slot].
// ---------------------------------------------------------------------------
__global__ void build_graph(const int* __restrict__ ei,
                            int* __restrict__ cnt_node,
                            int* __restrict__ bucket) {
    int e = blockIdx.x * blockDim.x + threadIdx.x;
    if (e >= EE) return;
    int src = ei[e];         // edge_index[0]
    int dst = ei[EE + e];    // edge_index[1]
    int slot = atomicAdd(&cnt_node[dst], 1);
    if (slot < CAP) bucket[dst * CAP + slot] = src;
}

// ---------------------------------------------------------------------------
// Weight prep: fp32 W[K][H] -> split-bf16 packed in LANE-LINEAR fragment order
// ---------------------------------------------------------------------------
struct PrepDesc { const float* src; unsigned short* dhi; unsigned short* dlo; int K; };
struct PrepArgs { PrepDesc d[9]; };

__global__ void prep_weights(PrepArgs pa) {
    PrepDesc de = pa.d[blockIdx.y];
    int total = de.K * HD;
    int KS = de.K >> 5;
    for (int idx = blockIdx.x * blockDim.x + threadIdx.x; idx < total;
         idx += gridDim.x * blockDim.x) {
        int k = idx / HD, h = idx - (idx / HD) * HD;   // src is [K][H]
        unsigned short hi, lo;
        split_bf16(de.src[idx], hi, lo);
        int nt = h >> 4, m = h & 15;
        int ks = k >> 5, quad = (k >> 3) & 3, e = k & 7;
        int lane = quad * 16 + m;
        int pidx = ((nt * KS + ks) * 64 + lane) * 8 + e;
        de.dhi[pidx] = hi;
        de.dlo[pidx] = lo;
    }
}

// ---------------------------------------------------------------------------
// Stage one nt-slice of weights (hi+lo tables) into LDS, cooperatively
// across 4 waves via global_load_lds (wave-uniform LDS base, per-lane gsrc).
// Slice layout: hi at [0, KS*512), lo at [KS*512, 2*KS*512).
// ---------------------------------------------------------------------------
template <int KS>
__device__ inline void stage_slice(const unsigned short* __restrict__ wh,
                                   const unsigned short* __restrict__ wl,
                                   int nt, unsigned short* dst, int wave, int lane) {
    if (KS == 4) {
        const unsigned short* gh = wh + nt * 2048 + wave * 512 + lane * 8;
        const unsigned short* gl = wl + nt * 2048 + wave * 512 + lane * 8;
        __builtin_amdgcn_global_load_lds((g1void*)gh, (l3void*)(dst + wave * 512), 16, 0, 0);
        __builtin_amdgcn_global_load_lds((g1void*)gl, (l3void*)(dst + 2048 + wave * 512), 16, 0, 0);
    } else {
        if (wave < 2) {
            const unsigned short* g = (wave == 0 ? wh : wl) + nt * 512 + lane * 8;
            __builtin_amdgcn_global_load_lds((g1void*)g, (l3void*)(dst + wave * 512), 16, 0, 0);
        }
    }
}

// ---------------------------------------------------------------------------
// Fused GIN layer (R13): LDS-staged weights (R10's win: 131->123us) COMBINED
// with R6's 3-blocks/CU geometry (best total, 459.9us).
//
// R10's dual-accumulator structure forced 16KB/wave transpose (80KB LDS,
// 2 blk/CU, Occ 18%); R6's per-s passes need only 8KB/wave (32KB) but paid
// per-wave VMEM weights. R13 = per-s passes + staged weights:
// LDS = 32KB transpose + 16KB staging = 48KB -> 3 blk/CU (12 waves/CU).
// Cost: each stage's 8 slices staged twice (192KB DMA/block vs R10's 96KB,
// still 6x less than R6's 1.15MB VMEM) and 48 barriers vs 26.
// Double-buffer walk is linear: slice t%8 lives in buf t%2 (t = s*8+nt);
// at t=15 the NEXT stage's slice 0 is staged -> seamless transitions.
// Gather = R10's verified loop; epilogues = R6's verified per-s versions.
// launch_bounds(256,3): VGPR ceiling ~170, natural ~100 (no R4-style clamp).
// ---------------------------------------------------------------------------
template <int K_IN, bool BF16IN, bool POOL>
__launch_bounds__(256, 3)
__global__ void gin_layer(const void* __restrict__ hin_,
                          const int* __restrict__ cnt_node,
                          const int* __restrict__ bucket,
                          const unsigned short* __restrict__ w1h, const unsigned short* __restrict__ w1l,
                          const float* __restrict__ b1,
                          const unsigned short* __restrict__ w2h, const unsigned short* __restrict__ w2l,
                          const float* __restrict__ b2,
                          const unsigned short* __restrict__ w3h, const unsigned short* __restrict__ w3l,
                          const float* __restrict__ b3,
                          unsigned short* __restrict__ out,   // bf16 activations (non-pool)
                          const int* __restrict__ batch,
                          float* __restrict__ pooled) {
    constexpr int KS1 = K_IN / 32;
    constexpr int UN = BF16IN ? 4 : 8;   // gather unroll depth
    // Per-wave swizzled transpose buffer (reused per s-half): 32 KB total.
    __shared__ unsigned int shp[4][16][128];
    // Double-buffered weight staging: 2 x 4096 hw = 16 KB. Block LDS = 48 KB.
    __shared__ unsigned short ldsW[2][4096];

    const int wave = threadIdx.x >> 6;
    const int lane = threadIdx.x & 63;
    const int m = lane & 15;      // node row within a 16-set / out-feature col
    const int quad = lane >> 4;   // 0..3
    const int nodeBase = blockIdx.x * 128 + wave * 32;

    const float* hf = (const float*)hin_;
    const unsigned short* hb = (const unsigned short*)hin_;

    // ---- fused aggregation (R10's verified loop): self + neighbors ----
    bf16x8 ah[2][KS1], al[2][KS1];
#pragma unroll
    for (int s = 0; s < 2; s++) {
        int node = nodeBase + s * 16 + m;
        node = node < NN ? node : NN - 1;
        float ag[KS1][8];
        if (BF16IN) {
            const unsigned short* rs = hb + (size_t)node * K_IN + quad * 8;
#pragma unroll
            for (int ks = 0; ks < KS1; ks++) {
                bf16x8 v = *(const bf16x8*)(rs + ks * 32);
#pragma unroll
                for (int e = 0; e < 8; e++) ag[ks][e] = bf2f((unsigned short)v[e]);
            }
        } else {
            const float* rs = hf + (size_t)node * K_IN + quad * 8;
            float4 v0 = *(const float4*)rs;
            float4 v1 = *(const float4*)(rs + 4);
            ag[0][0] = v0.x; ag[0][1] = v0.y; ag[0][2] = v0.z; ag[0][3] = v0.w;
            ag[0][4] = v1.x; ag[0][5] = v1.y; ag[0][6] = v1.z; ag[0][7] = v1.w;
        }
        int cnt = cnt_node[node];
        cnt = cnt < CAP ? cnt : CAP;
        const int* b = bucket + (size_t)node * CAP;
        int i = 0;
        if (BF16IN) {
            for (; i + UN <= cnt; i += UN) {
                bf16x8 v[UN][KS1];
#pragma unroll
                for (int j = 0; j < UN; j++) {
                    const unsigned short* r = hb + (size_t)b[i + j] * K_IN + quad * 8;
#pragma unroll
                    for (int ks = 0; ks < KS1; ks++)
                        v[j][ks] = *(const bf16x8*)(r + ks * 32);
                }
#pragma unroll
                for (int ks = 0; ks < KS1; ks++)
#pragma unroll
                    for (int e = 0; e < 8; e++) {
                        float t01 = bf2f((unsigned short)v[0][ks][e]) +
                                    bf2f((unsigned short)v[1][ks][e]);
                        float t23 = bf2f((unsigned short)v[2][ks][e]) +
                                    bf2f((unsigned short)v[3][ks][e]);
                        ag[ks][e] += t01 + t23;
                    }
            }
            for (; i < cnt; i++) {
                const unsigned short* r = hb + (size_t)b[i] * K_IN + quad * 8;
#pragma unroll
                for (int ks = 0; ks < KS1; ks++) {
                    bf16x8 v = *(const bf16x8*)(r + ks * 32);
#pragma unroll
                    for (int e = 0; e < 8; e++) ag[ks][e] += bf2f((unsigned short)v[e]);
                }
            }
        } else {
            for (; i + 8 <= cnt; i += 8) {
                float4 v0[8], v1[8];
#pragma unroll
                for (int j = 0; j < 8; j++) {
                    const float* r = hf + (size_t)b[i + j] * K_IN + quad * 8;
                    v0[j] = *(const float4*)r;
                    v1[j] = *(const float4*)(r + 4);
                }
#pragma unroll
                for (int e = 0; e < 4; e++) {
                    float s01 = (&v0[0].x)[e] + (&v0[1].x)[e] + (&v0[4].x)[e] + (&v0[5].x)[e];
                    float s23 = (&v0[2].x)[e] + (&v0[3].x)[e] + (&v0[6].x)[e] + (&v0[7].x)[e];
                    ag[0][e] += s01 + s23;
                }
#pragma unroll
                for (int e = 0; e < 4; e++) {
                    float s01 = (&v1[0].x)[e] + (&v1[1].x)[e] + (&v1[4].x)[e] + (&v1[5].x)[e];
                    float s23 = (&v1[2].x)[e] + (&v1[3].x)[e] + (&v1[6].x)[e] + (&v1[7].x)[e];
                    ag[0][e + 4] += s01 + s23;
                }
            }
            for (; i < cnt; i++) {
                const float* r = hf + (size_t)b[i] * K_IN + quad * 8;
                float4 v0 = *(const float4*)r;
                float4 v1 = *(const float4*)(r + 4);
                ag[0][0] += v0.x; ag[0][1] += v0.y; ag[0][2] += v0.z; ag[0][3] += v0.w;
                ag[0][4] += v1.x; ag[0][5] += v1.y; ag[0][6] += v1.z; ag[0][7] += v1.w;
            }
        }
#pragma unroll
        for (int ks = 0; ks < KS1; ks++) {
            bf16x8 vh, vl;
#pragma unroll
            for (int e = 0; e < 8; e++) {
                unsigned short hi, lo;
                split_bf16(ag[ks][e], hi, lo);
                vh[e] = (short)hi;
                vl[e] = (short)lo;
            }
            ah[s][ks] = vh;
            al[s][ks] = vl;
        }
    }

    bf16x8 a2h[2][4], a2l[2][4];
    const int fxm = (m & 7) << 2;          // read-side swizzle for row m

    // ================= stage 1: per-s passes over staged weights ============
    stage_slice<KS1>(w1h, w1l, 0, ldsW[0], wave, lane);
    __syncthreads();
#pragma unroll
    for (int s = 0; s < 2; s++) {
#pragma unroll 1
        for (int nt = 0; nt < 8; nt++) {
            int t = s * 8 + nt;
            int cur = t & 1;
            if (t < 15) stage_slice<KS1>(w1h, w1l, (nt + 1) & 7, ldsW[cur ^ 1], wave, lane);
            else        stage_slice<4>(w2h, w2l, 0, ldsW[cur ^ 1], wave, lane);
            bf16x8 bh[KS1], bl[KS1];
#pragma unroll
            for (int ks = 0; ks < KS1; ks++) {
                bh[ks] = *(const bf16x8*)&ldsW[cur][(ks * 64 + lane) * 8];
                bl[ks] = *(const bf16x8*)&ldsW[cur][KS1 * 512 + (ks * 64 + lane) * 8];
            }
            f32x4 c = {0.f, 0.f, 0.f, 0.f};
#pragma unroll
            for (int ks = 0; ks < KS1; ks++) {
                c = __builtin_amdgcn_mfma_f32_16x16x32_bf16(ah[s][ks], bh[ks], c, 0, 0, 0);
                c = __builtin_amdgcn_mfma_f32_16x16x32_bf16(al[s][ks], bh[ks], c, 0, 0, 0);
                c = __builtin_amdgcn_mfma_f32_16x16x32_bf16(ah[s][ks], bl[ks], c, 0, 0, 0);
            }
            float bj = b1[nt * 16 + m];
#pragma unroll
            for (int r = 0; r < 4; r++) {
                int row = quad * 4 + r;
                unsigned short hi, lo;
                split_bf16(fmaxf(c[r] + bj, 0.f), hi, lo);
                shp[wave][row][(nt * 16 + m) ^ ((row & 7) << 2)] =
                    (unsigned int)hi | ((unsigned int)lo << 16);
            }
            __syncthreads();
        }
        // per-s transpose read (wave-private buffer: no extra barrier needed)
#pragma unroll
        for (int ks = 0; ks < 4; ks++) {
            const unsigned int* rowp = &shp[wave][m][0];
            int base = ks * 32 + quad * 8;
            uint4 wa = *(const uint4*)&rowp[base ^ fxm];
            uint4 wb = *(const uint4*)&rowp[(base + 4) ^ fxm];
            union { unsigned int u[4]; bf16x8 v; } ch, cl;
            ch.u[0] = __builtin_amdgcn_perm(wa.y, wa.x, 0x05040100u);
            ch.u[1] = __builtin_amdgcn_perm(wa.w, wa.z, 0x05040100u);
            ch.u[2] = __builtin_amdgcn_perm(wb.y, wb.x, 0x05040100u);
            ch.u[3] = __builtin_amdgcn_perm(wb.w, wb.z, 0x05040100u);
            cl.u[0] = __builtin_amdgcn_perm(wa.y, wa.x, 0x07060302u);
            cl.u[1] = __builtin_amdgcn_perm(wa.w, wa.z, 0x07060302u);
            cl.u[2] = __builtin_amdgcn_perm(wb.y, wb.x, 0x07060302u);
            cl.u[3] = __builtin_amdgcn_perm(wb.w, wb.z, 0x07060302u);
            a2h[s][ks] = ch.v;
            a2l[s][ks] = cl.v;
        }
    }

    // ================= stage 2 =====================
#pragma unroll
    for (int s = 0; s < 2; s++) {
#pragma unroll 1
        for (int nt = 0; nt < 8; nt++) {
            int t = s * 8 + nt;
            int cur = t & 1;
            if (t < 15) stage_slice<4>(w2h, w2l, (nt + 1) & 7, ldsW[cur ^ 1], wave, lane);
            else        stage_slice<4>(w3h, w3l, 0, ldsW[cur ^ 1], wave, lane);
            bf16x8 bh[4], bl[4];
#pragma unroll
            for (int ks = 0; ks < 4; ks++) {
                bh[ks] = *(const bf16x8*)&ldsW[cur][(ks * 64 + lane) * 8];
                bl[ks] = *(const bf16x8*)&ldsW[cur][2048 + (ks * 64 + lane) * 8];
            }
            f32x4 c = {0.f, 0.f, 0.f, 0.f};
#pragma unroll
            for (int ks = 0; ks < 4; ks++) {
                c = __builtin_amdgcn_mfma_f32_16x16x32_bf16(a2h[s][ks], bh[ks], c, 0, 0, 0);
                c = __builtin_amdgcn_mfma_f32_16x16x32_bf16(a2l[s][ks], bh[ks], c, 0, 0, 0);
                c = __builtin_amdgcn_mfma_f32_16x16x32_bf16(a2h[s][ks], bl[ks], c, 0, 0, 0);
            }
            float bj = b2[nt * 16 + m];
#pragma unroll
            for (int r = 0; r < 4; r++) {
                int row = quad * 4 + r;
                unsigned short hi, lo;
                split_bf16(fmaxf(c[r] + bj, 0.f), hi, lo);
                shp[wave][row][(nt * 16 + m) ^ ((row & 7) << 2)] =
                    (unsigned int)hi | ((unsigned int)lo << 16);
            }
            __syncthreads();
        }
#pragma unroll
        for (int ks = 0; ks < 4; ks++) {
            const unsigned int* rowp = &shp[wave][m][0];
            int base = ks * 32 + quad * 8;
            uint4 wa = *(const uint4*)&rowp[base ^ fxm];
            uint4 wb = *(const uint4*)&rowp[(base + 4) ^ fxm];
            union { unsigned int u[4]; bf16x8 v; } ch, cl;
            ch.u[0] = __builtin_amdgcn_perm(wa.y, wa.x, 0x05040100u);
            ch.u[1] = __builtin_amdgcn_perm(wa.w, wa.z, 0x05040100u);
            ch.u[2] = __builtin_amdgcn_perm(wb.y, wb.x, 0x05040100u);
            ch.u[3] = __builtin_amdgcn_perm(wb.w, wb.z, 0x05040100u);
            cl.u[0] = __builtin_amdgcn_perm(wa.y, wa.x, 0x07060302u);
            cl.u[1] = __builtin_amdgcn_perm(wa.w, wa.z, 0x07060302u);
            cl.u[2] = __builtin_amdgcn_perm(wb.y, wb.x, 0x07060302u);
            cl.u[3] = __builtin_amdgcn_perm(wb.w, wb.z, 0x07060302u);
            a2h[s][ks] = ch.v;   // s's stage-2 inputs are dead: reuse for stage 3
            a2l[s][ks] = cl.v;
        }
    }

    // ================= stage 3 (per-s, epilogue folded after each pass) =====
#pragma unroll
    for (int s = 0; s < 2; s++) {
#pragma unroll 1
        for (int nt = 0; nt < 8; nt++) {
            int t = s * 8 + nt;
            int cur = t & 1;
            if (t < 15) stage_slice<4>(w3h, w3l, (nt + 1) & 7, ldsW[cur ^ 1], wave, lane);
            bf16x8 bh[4], bl[4];
#pragma unroll
            for (int ks = 0; ks < 4; ks++) {
                bh[ks] = *(const bf16x8*)&ldsW[cur][(ks * 64 + lane) * 8];
                bl[ks] = *(const bf16x8*)&ldsW[cur][2048 + (ks * 64 + lane) * 8];
            }
            f32x4 c = {0.f, 0.f, 0.f, 0.f};
#pragma unroll
            for (int ks = 0; ks < 4; ks++) {
                c = __builtin_amdgcn_mfma_f32_16x16x32_bf16(a2h[s][ks], bh[ks], c, 0, 0, 0);
                c = __builtin_amdgcn_mfma_f32_16x16x32_bf16(a2l[s][ks], bh[ks], c, 0, 0, 0);
                c = __builtin_amdgcn_mfma_f32_16x16x32_bf16(a2h[s][ks], bl[ks], c, 0, 0, 0);
            }
            float bj = b3[nt * 16 + m];
            if (POOL) {
                float* shf = (float*)&shp[wave][0][0];
#pragma unroll
                for (int r = 0; r < 4; r++) {
                    int row = quad * 4 + r;
                    shf[row * 128 + ((nt * 16 + m) ^ ((row & 7) << 2))] =
                        fmaxf(c[r] + bj, 0.f);
                }
            } else {
                unsigned short* sh16 = (unsigned short*)&shp[wave][0][0];
#pragma unroll
                for (int r = 0; r < 4; r++) {
                    int row = quad * 4 + r;
                    int hh = nt * 16 + m;                  // feature halfword idx
                    int w2 = (hh >> 1) ^ ((row & 7) << 2); // swizzled word
                    sh16[row * 256 + w2 * 2 + (hh & 1)] =
                        bf16_hi(fmaxf(c[r] + bj, 0.f));
                }
            }
            __syncthreads();
        }
        if (POOL) {
            // ---- fused mean-pool epilogue for this s-half ----
            float* shf = (float*)&shp[wave][0][0];
            int c0i = lane * 2;
            float run0 = 0.f, run1 = 0.f;
            int gp = -1;
            for (int rrow = 0; rrow < 16; rrow++) {
                int node = nodeBase + s * 16 + rrow;
                if (node >= NN) break;
                int g = batch[node];
                float2 xv = *(const float2*)&shf[rrow * 128 + (c0i ^ ((rrow & 7) << 2))];
                if (g != gp) {
                    if (gp >= 0) {
                        atomicAdd(&pooled[(size_t)gp * HD + c0i + 0], run0);
                        atomicAdd(&pooled[(size_t)gp * HD + c0i + 1], run1);
                    }
                    run0 = xv.x; run1 = xv.y; gp = g;
                } else {
                    run0 += xv.x; run1 += xv.y;
                }
            }
            if (gp >= 0) {
                atomicAdd(&pooled[(size_t)gp * HD + c0i + 0], run0);
                atomicAdd(&pooled[(size_t)gp * HD + c0i + 1], run1);
            }
        } else {
            // ---- coalesced bf16 row stores for this s-half ----
            unsigned short* sh16 = (unsigned short*)&shp[wave][0][0];  // [16][256]
#pragma unroll
            for (int io = 0; io < 4; io++) {
                int row16 = io * 4 + quad;
                int wbase = (m * 4) ^ ((row16 & 7) << 2);
                int n2 = nodeBase + s * 16 + row16;
                bf16x8 v = *(const bf16x8*)&sh16[row16 * 256 + wbase * 2];
                if (n2 < NN) *(bf16x8*)&out[(size_t)n2 * HD + m * 8] = v;
            }
        }
    }
}

// ---------------------------------------------------------------------------
// Classifier head: one block (128 threads) per graph.
// Graph node counts via binary search on the SORTED batch array.
// ---------------------------------------------------------------------------
__device__ inline int lb_batch(const int* __restrict__ batch, int key) {
    int lo = 0, hi = NN;
    while (lo < hi) {
        int mid = (lo + hi) >> 1;
        if (batch[mid] < key) lo = mid + 1; else hi = mid;
    }
    return lo;
}

__launch_bounds__(128)
__global__ void head(const float* __restrict__ pooled, const int* __restrict__ batch,
                     const float* __restrict__ fc0_w, const float* __restrict__ fc0_b,
                     const float* __restrict__ fc1_w, const float* __restrict__ fc1_b,
                     const float* __restrict__ out_w, const float* __restrict__ out_b,
                     float* __restrict__ out) {
    int g = blockIdx.x;
    int j = threadIdx.x;
    __shared__ float s0[HD];
    __shared__ float s1[HD];
    int c = lb_batch(batch, g + 1) - lb_batch(batch, g);
    float cf = (float)(c > 1 ? c : 1);
    s0[j] = pooled[(size_t)g * HD + j] / cf;
    __syncthreads();

    float acc = fc0_b[j];
    for (int k = 0; k < HD; k += 4) {
        float4 hv = *(const float4*)&s0[k];
        acc = fmaf(hv.x, fc0_w[(k + 0) * HD + j], acc);
        acc = fmaf(hv.y, fc0_w[(k + 1) * HD + j], acc);
        acc = fmaf(hv.z, fc0_w[(k + 2) * HD + j], acc);
        acc = fmaf(hv.w, fc0_w[(k + 3) * HD + j], acc);
    }
    s1[j] = fmaxf(acc, 0.0f);
    __syncthreads();

    acc = fc1_b[j];
    for (int k = 0; k < HD; k += 4) {
        float4 hv = *(const float4*)&s1[k];
        acc = fmaf(hv.x, fc1_w[(k + 0) * HD + j], acc);
        acc = fmaf(hv.y, fc1_w[(k + 1) * HD + j], acc);
        acc = fmaf(hv.z, fc1_w[(k + 2) * HD + j], acc);
        acc = fmaf(hv.w, fc1_w[(k + 3) * HD + j], acc);
    }
    float v = fmaxf(acc, 0.0f);

    float p0 = v * out_w[j * 2 + 0];
    float p1 = v * out_w[j * 2 + 1];
    __syncthreads();
    s0[j] = p0;
    s1[j] = p1;
    __syncthreads();
    for (int off = 64; off >= 1; off >>= 1) {
        if (j < off) {
            s0[j] += s0[j + off];
            s1[j] += s1[j + off];
        }
        __syncthreads();
    }
    if (j == 0) {
        out[(size_t)g * 2 + 0] = s0[0] + out_b[0];
        out[(size_t)g * 2 + 1] = s1[0] + out_b[1];
    }
}

// ---------------------------------------------------------------------------
extern "C" void kernel_launch(void* const* d_in, const int* in_sizes, int n_in,
                              void* d_out, int out_size, void* d_ws, size_t ws_size,
                              hipStream_t stream) {
    const float* x     = (const float*)d_in[0];
    const int*   ei    = (const int*)d_in[1];
    const int*   batch = (const int*)d_in[2];
    const float* cw[3][6];
    for (int i = 0; i < 3; i++)
        for (int k = 0; k < 6; k++) cw[i][k] = (const float*)d_in[3 + 6 * i + k];
    const float* fc0_w = (const float*)d_in[21];
    const float* fc0_b = (const float*)d_in[22];
    const float* fc1_w = (const float*)d_in[23];
    const float* fc1_b = (const float*)d_in[24];
    const float* out_w = (const float*)d_in[25];
    const float* out_b = (const float*)d_in[26];
    float* out = (float*)d_out;

    char* ws = (char*)d_ws;
    size_t off = 0;
    auto carve = [&](size_t bytes) {
        void* p = ws + off;
        off += (bytes + 255) & ~(size_t)255;
        return p;
    };
    // cnt_node and pooled contiguous (zeroed together by init_zero)
    int*   cnt_node = (int*)carve((size_t)NN * 4);
    float* pooled   = (float*)carve((size_t)GG * HD * 4);
    int*   bucket   = (int*)carve((size_t)NN * CAP * 4);
    unsigned short* hA = (unsigned short*)carve((size_t)NP * HD * 2);
    unsigned short* hB = (unsigned short*)carve((size_t)NP * HD * 2);
    unsigned short* wHi[9];
    unsigned short* wLo[9];
    int wK[9] = {F_IN, HD, HD, HD, HD, HD, HD, HD, HD};
    for (int i = 0; i < 9; i++) {
        wHi[i] = (unsigned short*)carve((size_t)wK[i] * HD * 2);
        wLo[i] = (unsigned short*)carve((size_t)wK[i] * HD * 2);
    }
    (void)ws_size;

    init_zero<<<(GG * HD + 255) / 256, 256, 0, stream>>>(cnt_node, pooled);
    build_graph<<<(EE + 255) / 256, 256, 0, stream>>>(ei, cnt_node, bucket);

    PrepArgs pa;
    for (int l = 0; l < 3; l++)
        for (int s = 0; s < 3; s++) {
            int i = l * 3 + s;
            pa.d[i].src = cw[l][2 * s];
            pa.d[i].dhi = wHi[i];
            pa.d[i].dlo = wLo[i];
            pa.d[i].K = wK[i];
        }
    prep_weights<<<dim3(16, 9), 256, 0, stream>>>(pa);

    const int blocks = NP / 128;  // 1172

    // ---- GIN layer 0 (K=32, fp32 in): x -> hA (bf16) ----
    gin_layer<F_IN, false, false><<<blocks, 256, 0, stream>>>(x, cnt_node, bucket,
        wHi[0], wLo[0], cw[0][1], wHi[1], wLo[1], cw[0][3], wHi[2], wLo[2], cw[0][5],
        hA, batch, pooled);
    // ---- GIN layer 1 (bf16 in): hA -> hB (bf16) ----
    gin_layer<HD, true, false><<<blocks, 256, 0, stream>>>(hA, cnt_node, bucket,
        wHi[3], wLo[3], cw[1][1], wHi[4], wLo[4], cw[1][3], wHi[5], wLo[5], cw[1][5],
        hB, batch, pooled);
    // ---- GIN layer 2 (bf16 in): hB -> pooled (fused mean-pool sum) ----
    gin_layer<HD, true, true><<<blocks, 256, 0, stream>>>(hB, cnt_node, bucket,
        wHi[6], wLo[6], cw[2][1], wHi[7], wLo[7], cw[2][3], wHi[8], wLo[8], cw[2][5],
        nullptr, batch, pooled);

    // ---- head ----
    head<<<GG, 128, 0, stream>>>(pooled, batch, fc0_w, fc0_b, fc1_w, fc1_b, out_w, out_b, out);
}

// Round 14
// 444.623 us; speedup vs baseline: 1.2453x; 1.0025x over previous
//
#include <hip/hip_runtime.h>
#include <hip/hip_bf16.h>

// Problem constants (fixed by the reference)
#define NN 150000      // nodes
#define EE 600000      // edges
#define F_IN 32        // input node features
#define HD 128         // hidden dim
#define GG 2048        // graphs
#define CAP 28         // max degree bucket capacity (Poisson(4): P(deg>=28) ~ 4e-18)
#define NP 150016      // NN rounded up to 128-node blocks: 1172*128

typedef __attribute__((ext_vector_type(8))) short bf16x8;
typedef __attribute__((ext_vector_type(4))) float f32x4;
typedef __attribute__((address_space(1))) const void g1void;
typedef __attribute__((address_space(3))) void l3void;

__device__ inline void split_bf16(float v, unsigned short& hi, unsigned short& lo) {
    __hip_bfloat16 h = __float2bfloat16(v);
    float hv = __bfloat162float(h);
    __hip_bfloat16 l = __float2bfloat16(v - hv);
    hi = *reinterpret_cast<unsigned short*>(&h);
    lo = *reinterpret_cast<unsigned short*>(&l);
}
__device__ inline unsigned short bf16_hi(float v) {
    __hip_bfloat16 h = __float2bfloat16(v);
    return *reinterpret_cast<unsigned short*>(&h);
}
__device__ inline float bf2f(unsigned short u) {
    union { unsigned int i; float f; } c;
    c.i = ((unsigned int)u) << 16;
    return c.f;
}

// ---------------------------------------------------------------------------
// Zero-init: cnt_node only (must precede build_graph's atomics)
// ---------------------------------------------------------------------------
__global__ void init_cnt(int* __restrict__ cnt_node) {
    int i = blockIdx.x * blockDim.x + threadIdx.x;
    if (i < NN) cnt_node[i] = 0;
}

// ---------------------------------------------------------------------------
// Weight prep descriptor
// ---------------------------------------------------------------------------
struct PrepDesc { const float* src; unsigned short* dhi; unsigned short* dlo; int K; };
struct PrepArgs { PrepDesc d[9]; };

// ---------------------------------------------------------------------------
// Merged setup kernel (R14): build_graph + prep_weights + pooled-zero in one
// grid. prep (~10us compute) and pooled-zero are independent of build's
// atomic storm -> they run CONCURRENTLY instead of serially after it.
// blocks [0,2344): edges; [2344,2488): weight prep; [2488,3512): zero pooled.
// ---------------------------------------------------------------------------
#define BG_BLOCKS 2344
#define PREP_BLOCKS 144
__global__ void setup_all(const int* __restrict__ ei,
                          int* __restrict__ cnt_node,
                          int* __restrict__ bucket,
                          PrepArgs pa,
                          float* __restrict__ pooled) {
    int bid = blockIdx.x;
    if (bid < BG_BLOCKS) {
        int e = bid * 256 + threadIdx.x;
        if (e >= EE) return;
        int src = ei[e];         // edge_index[0]
        int dst = ei[EE + e];    // edge_index[1]
        int slot = atomicAdd(&cnt_node[dst], 1);
        if (slot < CAP) bucket[dst * CAP + slot] = src;
    } else if (bid < BG_BLOCKS + PREP_BLOCKS) {
        int pb = bid - BG_BLOCKS;
        PrepDesc de = pa.d[pb >> 4];
        int px = pb & 15;
        int total = de.K * HD;
        int KS = de.K >> 5;
        for (int idx = px * 256 + threadIdx.x; idx < total; idx += 16 * 256) {
            int k = idx / HD, h = idx - (idx / HD) * HD;   // src is [K][H]
            unsigned short hi, lo;
            split_bf16(de.src[idx], hi, lo);
            int nt = h >> 4, m = h & 15;
            int ks = k >> 5, quad = (k >> 3) & 3, e = k & 7;
            int lane = quad * 16 + m;
            int pidx = ((nt * KS + ks) * 64 + lane) * 8 + e;
            de.dhi[pidx] = hi;
            de.dlo[pidx] = lo;
        }
    } else {
        int i = (bid - BG_BLOCKS - PREP_BLOCKS) * 256 + threadIdx.x;
        if (i < GG * HD) pooled[i] = 0.f;
    }
}

// ---------------------------------------------------------------------------
// Stage one nt-slice of weights (hi+lo tables) into LDS, cooperatively
// across 4 waves via global_load_lds (wave-uniform LDS base, per-lane gsrc).
// Slice layout: hi at [0, KS*512), lo at [KS*512, 2*KS*512).
// ---------------------------------------------------------------------------
template <int KS>
__device__ inline void stage_slice(const unsigned short* __restrict__ wh,
                                   const unsigned short* __restrict__ wl,
                                   int nt, unsigned short* dst, int wave, int lane) {
    if (KS == 4) {
        const unsigned short* gh = wh + nt * 2048 + wave * 512 + lane * 8;
        const unsigned short* gl = wl + nt * 2048 + wave * 512 + lane * 8;
        __builtin_amdgcn_global_load_lds((g1void*)gh, (l3void*)(dst + wave * 512), 16, 0, 0);
        __builtin_amdgcn_global_load_lds((g1void*)gl, (l3void*)(dst + 2048 + wave * 512), 16, 0, 0);
    } else {
        if (wave < 2) {
            const unsigned short* g = (wave == 0 ? wh : wl) + nt * 512 + lane * 8;
            __builtin_amdgcn_global_load_lds((g1void*)g, (l3void*)(dst + wave * 512), 16, 0, 0);
        }
    }
}

// ---------------------------------------------------------------------------
// Fused GIN layer (R13, VERBATIM — 116.5-117.6us/layer verified, Occ 26%,
// VGPR 76, WRITE 11.3MB no-spill): per-s passes + LDS-staged weights.
// LDS = 32KB transpose + 16KB staging = 48KB -> 3 blk/CU (12 waves/CU).
// ---------------------------------------------------------------------------
template <int K_IN, bool BF16IN, bool POOL>
__launch_bounds__(256, 3)
__global__ void gin_layer(const void* __restrict__ hin_,
                          const int* __restrict__ cnt_node,
                          const int* __restrict__ bucket,
                          const unsigned short* __restrict__ w1h, const unsigned short* __restrict__ w1l,
                          const float* __restrict__ b1,
                          const unsigned short* __restrict__ w2h, const unsigned short* __restrict__ w2l,
                          const float* __restrict__ b2,
                          const unsigned short* __restrict__ w3h, const unsigned short* __restrict__ w3l,
                          const float* __restrict__ b3,
                          unsigned short* __restrict__ out,   // bf16 activations (non-pool)
                          const int* __restrict__ batch,
                          float* __restrict__ pooled) {
    constexpr int KS1 = K_IN / 32;
    constexpr int UN = BF16IN ? 4 : 8;   // gather unroll depth
    // Per-wave swizzled transpose buffer (reused per s-half): 32 KB total.
    __shared__ unsigned int shp[4][16][128];
    // Double-buffered weight staging: 2 x 4096 hw = 16 KB. Block LDS = 48 KB.
    __shared__ unsigned short ldsW[2][4096];

    const int wave = threadIdx.x >> 6;
    const int lane = threadIdx.x & 63;
    const int m = lane & 15;      // node row within a 16-set / out-feature col
    const int quad = lane >> 4;   // 0..3
    const int nodeBase = blockIdx.x * 128 + wave * 32;

    const float* hf = (const float*)hin_;
    const unsigned short* hb = (const unsigned short*)hin_;

    // ---- fused aggregation: self + neighbors ----
    bf16x8 ah[2][KS1], al[2][KS1];
#pragma unroll
    for (int s = 0; s < 2; s++) {
        int node = nodeBase + s * 16 + m;
        node = node < NN ? node : NN - 1;
        float ag[KS1][8];
        if (BF16IN) {
            const unsigned short* rs = hb + (size_t)node * K_IN + quad * 8;
#pragma unroll
            for (int ks = 0; ks < KS1; ks++) {
                bf16x8 v = *(const bf16x8*)(rs + ks * 32);
#pragma unroll
                for (int e = 0; e < 8; e++) ag[ks][e] = bf2f((unsigned short)v[e]);
            }
        } else {
            const float* rs = hf + (size_t)node * K_IN + quad * 8;
            float4 v0 = *(const float4*)rs;
            float4 v1 = *(const float4*)(rs + 4);
            ag[0][0] = v0.x; ag[0][1] = v0.y; ag[0][2] = v0.z; ag[0][3] = v0.w;
            ag[0][4] = v1.x; ag[0][5] = v1.y; ag[0][6] = v1.z; ag[0][7] = v1.w;
        }
        int cnt = cnt_node[node];
        cnt = cnt < CAP ? cnt : CAP;
        const int* b = bucket + (size_t)node * CAP;
        int i = 0;
        if (BF16IN) {
            for (; i + UN <= cnt; i += UN) {
                bf16x8 v[UN][KS1];
#pragma unroll
                for (int j = 0; j < UN; j++) {
                    const unsigned short* r = hb + (size_t)b[i + j] * K_IN + quad * 8;
#pragma unroll
                    for (int ks = 0; ks < KS1; ks++)
                        v[j][ks] = *(const bf16x8*)(r + ks * 32);
                }
#pragma unroll
                for (int ks = 0; ks < KS1; ks++)
#pragma unroll
                    for (int e = 0; e < 8; e++) {
                        float t01 = bf2f((unsigned short)v[0][ks][e]) +
                                    bf2f((unsigned short)v[1][ks][e]);
                        float t23 = bf2f((unsigned short)v[2][ks][e]) +
                                    bf2f((unsigned short)v[3][ks][e]);
                        ag[ks][e] += t01 + t23;
                    }
            }
            for (; i < cnt; i++) {
                const unsigned short* r = hb + (size_t)b[i] * K_IN + quad * 8;
#pragma unroll
                for (int ks = 0; ks < KS1; ks++) {
                    bf16x8 v = *(const bf16x8*)(r + ks * 32);
#pragma unroll
                    for (int e = 0; e < 8; e++) ag[ks][e] += bf2f((unsigned short)v[e]);
                }
            }
        } else {
            for (; i + 8 <= cnt; i += 8) {
                float4 v0[8], v1[8];
#pragma unroll
                for (int j = 0; j < 8; j++) {
                    const float* r = hf + (size_t)b[i + j] * K_IN + quad * 8;
                    v0[j] = *(const float4*)r;
                    v1[j] = *(const float4*)(r + 4);
                }
#pragma unroll
                for (int e = 0; e < 4; e++) {
                    float s01 = (&v0[0].x)[e] + (&v0[1].x)[e] + (&v0[4].x)[e] + (&v0[5].x)[e];
                    float s23 = (&v0[2].x)[e] + (&v0[3].x)[e] + (&v0[6].x)[e] + (&v0[7].x)[e];
                    ag[0][e] += s01 + s23;
                }
#pragma unroll
                for (int e = 0; e < 4; e++) {
                    float s01 = (&v1[0].x)[e] + (&v1[1].x)[e] + (&v1[4].x)[e] + (&v1[5].x)[e];
                    float s23 = (&v1[2].x)[e] + (&v1[3].x)[e] + (&v1[6].x)[e] + (&v1[7].x)[e];
                    ag[0][e + 4] += s01 + s23;
                }
            }
            for (; i < cnt; i++) {
                const float* r = hf + (size_t)b[i] * K_IN + quad * 8;
                float4 v0 = *(const float4*)r;
                float4 v1 = *(const float4*)(r + 4);
                ag[0][0] += v0.x; ag[0][1] += v0.y; ag[0][2] += v0.z; ag[0][3] += v0.w;
                ag[0][4] += v1.x; ag[0][5] += v1.y; ag[0][6] += v1.z; ag[0][7] += v1.w;
            }
        }
#pragma unroll
        for (int ks = 0; ks < KS1; ks++) {
            bf16x8 vh, vl;
#pragma unroll
            for (int e = 0; e < 8; e++) {
                unsigned short hi, lo;
                split_bf16(ag[ks][e], hi, lo);
                vh[e] = (short)hi;
                vl[e] = (short)lo;
            }
            ah[s][ks] = vh;
            al[s][ks] = vl;
        }
    }

    bf16x8 a2h[2][4], a2l[2][4];
    const int fxm = (m & 7) << 2;          // read-side swizzle for row m

    // ================= stage 1: per-s passes over staged weights ============
    stage_slice<KS1>(w1h, w1l, 0, ldsW[0], wave, lane);
    __syncthreads();
#pragma unroll
    for (int s = 0; s < 2; s++) {
#pragma unroll 1
        for (int nt = 0; nt < 8; nt++) {
            int t = s * 8 + nt;
            int cur = t & 1;
            if (t < 15) stage_slice<KS1>(w1h, w1l, (nt + 1) & 7, ldsW[cur ^ 1], wave, lane);
            else        stage_slice<4>(w2h, w2l, 0, ldsW[cur ^ 1], wave, lane);
            bf16x8 bh[KS1], bl[KS1];
#pragma unroll
            for (int ks = 0; ks < KS1; ks++) {
                bh[ks] = *(const bf16x8*)&ldsW[cur][(ks * 64 + lane) * 8];
                bl[ks] = *(const bf16x8*)&ldsW[cur][KS1 * 512 + (ks * 64 + lane) * 8];
            }
            f32x4 c = {0.f, 0.f, 0.f, 0.f};
#pragma unroll
            for (int ks = 0; ks < KS1; ks++) {
                c = __builtin_amdgcn_mfma_f32_16x16x32_bf16(ah[s][ks], bh[ks], c, 0, 0, 0);
                c = __builtin_amdgcn_mfma_f32_16x16x32_bf16(al[s][ks], bh[ks], c, 0, 0, 0);
                c = __builtin_amdgcn_mfma_f32_16x16x32_bf16(ah[s][ks], bl[ks], c, 0, 0, 0);
            }
            float bj = b1[nt * 16 + m];
#pragma unroll
            for (int r = 0; r < 4; r++) {
                int row = quad * 4 + r;
                unsigned short hi, lo;
                split_bf16(fmaxf(c[r] + bj, 0.f), hi, lo);
                shp[wave][row][(nt * 16 + m) ^ ((row & 7) << 2)] =
                    (unsigned int)hi | ((unsigned int)lo << 16);
            }
            __syncthreads();
        }
        // per-s transpose read (wave-private buffer: no extra barrier needed)
#pragma unroll
        for (int ks = 0; ks < 4; ks++) {
            const unsigned int* rowp = &shp[wave][m][0];
            int base = ks * 32 + quad * 8;
            uint4 wa = *(const uint4*)&rowp[base ^ fxm];
            uint4 wb = *(const uint4*)&rowp[(base + 4) ^ fxm];
            union { unsigned int u[4]; bf16x8 v; } ch, cl;
            ch.u[0] = __builtin_amdgcn_perm(wa.y, wa.x, 0x05040100u);
            ch.u[1] = __builtin_amdgcn_perm(wa.w, wa.z, 0x05040100u);
            ch.u[2] = __builtin_amdgcn_perm(wb.y, wb.x, 0x05040100u);
            ch.u[3] = __builtin_amdgcn_perm(wb.w, wb.z, 0x05040100u);
            cl.u[0] = __builtin_amdgcn_perm(wa.y, wa.x, 0x07060302u);
            cl.u[1] = __builtin_amdgcn_perm(wa.w, wa.z, 0x07060302u);
            cl.u[2] = __builtin_amdgcn_perm(wb.y, wb.x, 0x07060302u);
            cl.u[3] = __builtin_amdgcn_perm(wb.w, wb.z, 0x07060302u);
            a2h[s][ks] = ch.v;
            a2l[s][ks] = cl.v;
        }
    }

    // ================= stage 2 =====================
#pragma unroll
    for (int s = 0; s < 2; s++) {
#pragma unroll 1
        for (int nt = 0; nt < 8; nt++) {
            int t = s * 8 + nt;
            int cur = t & 1;
            if (t < 15) stage_slice<4>(w2h, w2l, (nt + 1) & 7, ldsW[cur ^ 1], wave, lane);
            else        stage_slice<4>(w3h, w3l, 0, ldsW[cur ^ 1], wave, lane);
            bf16x8 bh[4], bl[4];
#pragma unroll
            for (int ks = 0; ks < 4; ks++) {
                bh[ks] = *(const bf16x8*)&ldsW[cur][(ks * 64 + lane) * 8];
                bl[ks] = *(const bf16x8*)&ldsW[cur][2048 + (ks * 64 + lane) * 8];
            }
            f32x4 c = {0.f, 0.f, 0.f, 0.f};
#pragma unroll
            for (int ks = 0; ks < 4; ks++) {
                c = __builtin_amdgcn_mfma_f32_16x16x32_bf16(a2h[s][ks], bh[ks], c, 0, 0, 0);
                c = __builtin_amdgcn_mfma_f32_16x16x32_bf16(a2l[s][ks], bh[ks], c, 0, 0, 0);
                c = __builtin_amdgcn_mfma_f32_16x16x32_bf16(a2h[s][ks], bl[ks], c, 0, 0, 0);
            }
            float bj = b2[nt * 16 + m];
#pragma unroll
            for (int r = 0; r < 4; r++) {
                int row = quad * 4 + r;
                unsigned short hi, lo;
                split_bf16(fmaxf(c[r] + bj, 0.f), hi, lo);
                shp[wave][row][(nt * 16 + m) ^ ((row & 7) << 2)] =
                    (unsigned int)hi | ((unsigned int)lo << 16);
            }
            __syncthreads();
        }
#pragma unroll
        for (int ks = 0; ks < 4; ks++) {
            const unsigned int* rowp = &shp[wave][m][0];
            int base = ks * 32 + quad * 8;
            uint4 wa = *(const uint4*)&rowp[base ^ fxm];
            uint4 wb = *(const uint4*)&rowp[(base + 4) ^ fxm];
            union { unsigned int u[4]; bf16x8 v; } ch, cl;
            ch.u[0] = __builtin_amdgcn_perm(wa.y, wa.x, 0x05040100u);
            ch.u[1] = __builtin_amdgcn_perm(wa.w, wa.z, 0x05040100u);
            ch.u[2] = __builtin_amdgcn_perm(wb.y, wb.x, 0x05040100u);
            ch.u[3] = __builtin_amdgcn_perm(wb.w, wb.z, 0x05040100u);
            cl.u[0] = __builtin_amdgcn_perm(wa.y, wa.x, 0x07060302u);
            cl.u[1] = __builtin_amdgcn_perm(wa.w, wa.z, 0x07060302u);
            cl.u[2] = __builtin_amdgcn_perm(wb.y, wb.x, 0x07060302u);
            cl.u[3] = __builtin_amdgcn_perm(wb.w, wb.z, 0x07060302u);
            a2h[s][ks] = ch.v;   // s's stage-2 inputs are dead: reuse for stage 3
            a2l[s][ks] = cl.v;
        }
    }

    // ================= stage 3 (per-s, epilogue folded after each pass) =====
#pragma unroll
    for (int s = 0; s < 2; s++) {
#pragma unroll 1
        for (int nt = 0; nt < 8; nt++) {
            int t = s * 8 + nt;
            int cur = t & 1;
            if (t < 15) stage_slice<4>(w3h, w3l, (nt + 1) & 7, ldsW[cur ^ 1], wave, lane);
            bf16x8 bh[4], bl[4];
#pragma unroll
            for (int ks = 0; ks < 4; ks++) {
                bh[ks] = *(const bf16x8*)&ldsW[cur][(ks * 64 + lane) * 8];
                bl[ks] = *(const bf16x8*)&ldsW[cur][2048 + (ks * 64 + lane) * 8];
            }
            f32x4 c = {0.f, 0.f, 0.f, 0.f};
#pragma unroll
            for (int ks = 0; ks < 4; ks++) {
                c = __builtin_amdgcn_mfma_f32_16x16x32_bf16(a2h[s][ks], bh[ks], c, 0, 0, 0);
                c = __builtin_amdgcn_mfma_f32_16x16x32_bf16(a2l[s][ks], bh[ks], c, 0, 0, 0);
                c = __builtin_amdgcn_mfma_f32_16x16x32_bf16(a2h[s][ks], bl[ks], c, 0, 0, 0);
            }
            float bj = b3[nt * 16 + m];
            if (POOL) {
                float* shf = (float*)&shp[wave][0][0];
#pragma unroll
                for (int r = 0; r < 4; r++) {
                    int row = quad * 4 + r;
                    shf[row * 128 + ((nt * 16 + m) ^ ((row & 7) << 2))] =
                        fmaxf(c[r] + bj, 0.f);
                }
            } else {
                unsigned short* sh16 = (unsigned short*)&shp[wave][0][0];
#pragma unroll
                for (int r = 0; r < 4; r++) {
                    int row = quad * 4 + r;
                    int hh = nt * 16 + m;                  // feature halfword idx
                    int w2 = (hh >> 1) ^ ((row & 7) << 2); // swizzled word
                    sh16[row * 256 + w2 * 2 + (hh & 1)] =
                        bf16_hi(fmaxf(c[r] + bj, 0.f));
                }
            }
            __syncthreads();
        }
        if (POOL) {
            // ---- fused mean-pool epilogue for this s-half ----
            float* shf = (float*)&shp[wave][0][0];
            int c0i = lane * 2;
            float run0 = 0.f, run1 = 0.f;
            int gp = -1;
            for (int rrow = 0; rrow < 16; rrow++) {
                int node = nodeBase + s * 16 + rrow;
                if (node >= NN) break;
                int g = batch[node];
                float2 xv = *(const float2*)&shf[rrow * 128 + (c0i ^ ((rrow & 7) << 2))];
                if (g != gp) {
                    if (gp >= 0) {
                        atomicAdd(&pooled[(size_t)gp * HD + c0i + 0], run0);
                        atomicAdd(&pooled[(size_t)gp * HD + c0i + 1], run1);
                    }
                    run0 = xv.x; run1 = xv.y; gp = g;
                } else {
                    run0 += xv.x; run1 += xv.y;
                }
            }
            if (gp >= 0) {
                atomicAdd(&pooled[(size_t)gp * HD + c0i + 0], run0);
                atomicAdd(&pooled[(size_t)gp * HD + c0i + 1], run1);
            }
        } else {
            // ---- coalesced bf16 row stores for this s-half ----
            unsigned short* sh16 = (unsigned short*)&shp[wave][0][0];  // [16][256]
#pragma unroll
            for (int io = 0; io < 4; io++) {
                int row16 = io * 4 + quad;
                int wbase = (m * 4) ^ ((row16 & 7) << 2);
                int n2 = nodeBase + s * 16 + row16;
                bf16x8 v = *(const bf16x8*)&sh16[row16 * 256 + wbase * 2];
                if (n2 < NN) *(bf16x8*)&out[(size_t)n2 * HD + m * 8] = v;
            }
        }
    }
}

// ---------------------------------------------------------------------------
// Classifier head: one block (128 threads) per graph.
// Graph node counts via binary search on the SORTED batch array.
// ---------------------------------------------------------------------------
__device__ inline int lb_batch(const int* __restrict__ batch, int key) {
    int lo = 0, hi = NN;
    while (lo < hi) {
        int mid = (lo + hi) >> 1;
        if (batch[mid] < key) lo = mid + 1; else hi = mid;
    }
    return lo;
}

__launch_bounds__(128)
__global__ void head(const float* __restrict__ pooled, const int* __restrict__ batch,
                     const float* __restrict__ fc0_w, const float* __restrict__ fc0_b,
                     const float* __restrict__ fc1_w, const float* __restrict__ fc1_b,
                     const float* __restrict__ out_w, const float* __restrict__ out_b,
                     float* __restrict__ out) {
    int g = blockIdx.x;
    int j = threadIdx.x;
    __shared__ float s0[HD];
    __shared__ float s1[HD];
    int c = lb_batch(batch, g + 1) - lb_batch(batch, g);
    float cf = (float)(c > 1 ? c : 1);
    s0[j] = pooled[(size_t)g * HD + j] / cf;
    __syncthreads();

    float acc = fc0_b[j];
    for (int k = 0; k < HD; k += 4) {
        float4 hv = *(const float4*)&s0[k];
        acc = fmaf(hv.x, fc0_w[(k + 0) * HD + j], acc);
        acc = fmaf(hv.y, fc0_w[(k + 1) * HD + j], acc);
        acc = fmaf(hv.z, fc0_w[(k + 2) * HD + j], acc);
        acc = fmaf(hv.w, fc0_w[(k + 3) * HD + j], acc);
    }
    s1[j] = fmaxf(acc, 0.0f);
    __syncthreads();

    acc = fc1_b[j];
    for (int k = 0; k < HD; k += 4) {
        float4 hv = *(const float4*)&s1[k];
        acc = fmaf(hv.x, fc1_w[(k + 0) * HD + j], acc);
        acc = fmaf(hv.y, fc1_w[(k + 1) * HD + j], acc);
        acc = fmaf(hv.z, fc1_w[(k + 2) * HD + j], acc);
        acc = fmaf(hv.w, fc1_w[(k + 3) * HD + j], acc);
    }
    float v = fmaxf(acc, 0.0f);

    float p0 = v * out_w[j * 2 + 0];
    float p1 = v * out_w[j * 2 + 1];
    __syncthreads();
    s0[j] = p0;
    s1[j] = p1;
    __syncthreads();
    for (int off = 64; off >= 1; off >>= 1) {
        if (j < off) {
            s0[j] += s0[j + off];
            s1[j] += s1[j + off];
        }
        __syncthreads();
    }
    if (j == 0) {
        out[(size_t)g * 2 + 0] = s0[0] + out_b[0];
        out[(size_t)g * 2 + 1] = s1[0] + out_b[1];
    }
}

// ---------------------------------------------------------------------------
extern "C" void kernel_launch(void* const* d_in, const int* in_sizes, int n_in,
                              void* d_out, int out_size, void* d_ws, size_t ws_size,
                              hipStream_t stream) {
    const float* x     = (const float*)d_in[0];
    const int*   ei    = (const int*)d_in[1];
    const int*   batch = (const int*)d_in[2];
    const float* cw[3][6];
    for (int i = 0; i < 3; i++)
        for (int k = 0; k < 6; k++) cw[i][k] = (const float*)d_in[3 + 6 * i + k];
    const float* fc0_w = (const float*)d_in[21];
    const float* fc0_b = (const float*)d_in[22];
    const float* fc1_w = (const float*)d_in[23];
    const float* fc1_b = (const float*)d_in[24];
    const float* out_w = (const float*)d_in[25];
    const float* out_b = (const float*)d_in[26];
    float* out = (float*)d_out;

    char* ws = (char*)d_ws;
    size_t off = 0;
    auto carve = [&](size_t bytes) {
        void* p = ws + off;
        off += (bytes + 255) & ~(size_t)255;
        return p;
    };
    int*   cnt_node = (int*)carve((size_t)NN * 4);
    float* pooled   = (float*)carve((size_t)GG * HD * 4);
    int*   bucket   = (int*)carve((size_t)NN * CAP * 4);
    unsigned short* hA = (unsigned short*)carve((size_t)NP * HD * 2);
    unsigned short* hB = (unsigned short*)carve((size_t)NP * HD * 2);
    unsigned short* wHi[9];
    unsigned short* wLo[9];
    int wK[9] = {F_IN, HD, HD, HD, HD, HD, HD, HD, HD};
    for (int i = 0; i < 9; i++) {
        wHi[i] = (unsigned short*)carve((size_t)wK[i] * HD * 2);
        wLo[i] = (unsigned short*)carve((size_t)wK[i] * HD * 2);
    }
    (void)ws_size;

    PrepArgs pa;
    for (int l = 0; l < 3; l++)
        for (int s = 0; s < 3; s++) {
            int i = l * 3 + s;
            pa.d[i].src = cw[l][2 * s];
            pa.d[i].dhi = wHi[i];
            pa.d[i].dlo = wLo[i];
            pa.d[i].K = wK[i];
        }

    // 1) zero cnt_node (precondition for build's atomics)
    init_cnt<<<(NN + 255) / 256, 256, 0, stream>>>(cnt_node);
    // 2) merged: build_graph || prep_weights || pooled-zero (concurrent)
    setup_all<<<BG_BLOCKS + PREP_BLOCKS + (GG * HD + 255) / 256, 256, 0, stream>>>(
        ei, cnt_node, bucket, pa, pooled);

    const int blocks = NP / 128;  // 1172

    // ---- GIN layer 0 (K=32, fp32 in): x -> hA (bf16) ----
    gin_layer<F_IN, false, false><<<blocks, 256, 0, stream>>>(x, cnt_node, bucket,
        wHi[0], wLo[0], cw[0][1], wHi[1], wLo[1], cw[0][3], wHi[2], wLo[2], cw[0][5],
        hA, batch, pooled);
    // ---- GIN layer 1 (bf16 in): hA -> hB (bf16) ----
    gin_layer<HD, true, false><<<blocks, 256, 0, stream>>>(hA, cnt_node, bucket,
        wHi[3], wLo[3], cw[1][1], wHi[4], wLo[4], cw[1][3], wHi[5], wLo[5], cw[1][5],
        hB, batch, pooled);
    // ---- GIN layer 2 (bf16 in): hB -> pooled (fused mean-pool sum) ----
    gin_layer<HD, true, true><<<blocks, 256, 0, stream>>>(hB, cnt_node, bucket,
        wHi[6], wLo[6], cw[2][1], wHi[7], wLo[7], cw[2][3], wHi[8], wLo[8], cw[2][5],
        nullptr, batch, pooled);

    // ---- head ----
    head<<<GG, 128, 0, stream>>>(pooled, batch, fc0_w, fc0_b, fc1_w, fc1_b, out_w, out_b, out);
}